// Round 1
// baseline (2425.633 us; speedup 1.0000x reference)
//
#include <hip/hip_runtime.h>

#define DM 128          // model dim
#define KS 20           // attention samples
#define NHEAD 4
#define DH 32

// ---------------------------------------------------------------------------
// Generic tiled SGEMM: out[M][CO] = X[M][CI] @ W[CO][CI]^T + bias, opt ReLU.
// SPLIT>0: X columns [0,SPLIT) come from X0 (row stride SPLIT), columns
// [SPLIT,CI) from X1 (row stride CI-SPLIT)  -> fused concat input.
// Block tile 64x64, thread tile 4x4, BK=16.
// ---------------------------------------------------------------------------
template <int CI, int CO, bool RELU, int SPLIT>
__global__ __launch_bounds__(256) void gemm_kernel(
    const float* __restrict__ X0, const float* __restrict__ X1,
    const float* __restrict__ W, const float* __restrict__ bias,
    float* __restrict__ out, int M)
{
    constexpr int BK = 16;
    __shared__ float Xs[BK][68];   // [k][row], padded
    __shared__ float Ws[BK][68];   // [k][col], padded

    const int tid   = threadIdx.x;
    const int row_t = tid >> 4;    // 0..15
    const int col_t = tid & 15;    // 0..15
    const int m0 = blockIdx.x * 64;
    const int c0 = blockIdx.y * 64;
    const int lr = tid >> 2;       // 0..63 (tile row / tile col for loads)
    const int lq = tid & 3;        // 0..3  (k chunk)

    float acc[4][4] = {};

    for (int k0 = 0; k0 < CI; k0 += BK) {
        // ---- stage X tile ----
        {
            const int gr = m0 + lr;
            int gk = k0 + lq * 4;
            const float* src = X0;
            int stride = (SPLIT > 0) ? SPLIT : CI;
            if (SPLIT > 0 && gk >= SPLIT) { src = X1; gk -= SPLIT; stride = CI - SPLIT; }
            float4 xv = make_float4(0.f, 0.f, 0.f, 0.f);
            if (gr < M) xv = *(const float4*)(src + (size_t)gr * stride + gk);
            const int kl = lq * 4;
            Xs[kl + 0][lr] = xv.x; Xs[kl + 1][lr] = xv.y;
            Xs[kl + 2][lr] = xv.z; Xs[kl + 3][lr] = xv.w;
        }
        // ---- stage W tile ----
        {
            const int gc = c0 + lr;
            const int gk = k0 + lq * 4;
            float4 wv = *(const float4*)(W + (size_t)gc * CI + gk);
            const int kl = lq * 4;
            Ws[kl + 0][lr] = wv.x; Ws[kl + 1][lr] = wv.y;
            Ws[kl + 2][lr] = wv.z; Ws[kl + 3][lr] = wv.w;
        }
        __syncthreads();

        #pragma unroll
        for (int kk = 0; kk < BK; ++kk) {
            const float4 av = *(const float4*)&Xs[kk][row_t * 4];
            const float4 bv = *(const float4*)&Ws[kk][col_t * 4];
            const float a[4] = {av.x, av.y, av.z, av.w};
            const float b[4] = {bv.x, bv.y, bv.z, bv.w};
            #pragma unroll
            for (int i = 0; i < 4; ++i)
                #pragma unroll
                for (int j = 0; j < 4; ++j)
                    acc[i][j] += a[i] * b[j];
        }
        __syncthreads();
    }

    const float4 bq = *(const float4*)(bias + c0 + col_t * 4);
    const float bb[4] = {bq.x, bq.y, bq.z, bq.w};
    #pragma unroll
    for (int i = 0; i < 4; ++i) {
        const int r = m0 + row_t * 4 + i;
        if (r < M) {
            float4 o;
            float v0 = acc[i][0] + bb[0];
            float v1 = acc[i][1] + bb[1];
            float v2 = acc[i][2] + bb[2];
            float v3 = acc[i][3] + bb[3];
            if (RELU) {
                v0 = fmaxf(v0, 0.f); v1 = fmaxf(v1, 0.f);
                v2 = fmaxf(v2, 0.f); v3 = fmaxf(v3, 0.f);
            }
            o.x = v0; o.y = v1; o.z = v2; o.w = v3;
            *(float4*)(out + (size_t)r * CO + c0 + col_t * 4) = o;
        }
    }
}

// ---------------------------------------------------------------------------
// Fused sampled attention. qkv[N][384] = [q|k|v]. 128 threads per node
// (2 nodes / 256-thread block). Head = t/32; shuffle-reduce dot products
// within 32-lane head groups; scores + V fragments live in registers.
// ---------------------------------------------------------------------------
__global__ __launch_bounds__(256) void attn_kernel(
    const float* __restrict__ qkv, const int* __restrict__ samples,
    float* __restrict__ ctx, int n)
{
    const int node = blockIdx.x * 2 + (threadIdx.x >> 7);
    const int t = threadIdx.x & 127;
    if (node >= n) return;

    const float scale = 0.17677669529663687f;  // 1/sqrt(32)
    const float qv = qkv[(size_t)node * 384 + t];

    float sc[KS], vv[KS];
    #pragma unroll
    for (int j = 0; j < KS; ++j) {
        const int row = samples[node * KS + j];
        const size_t base = (size_t)row * 384;
        const float kv = qkv[base + 128 + t];
        vv[j] = qkv[base + 256 + t];
        float p = qv * kv;
        p += __shfl_xor(p, 16, 32);
        p += __shfl_xor(p, 8, 32);
        p += __shfl_xor(p, 4, 32);
        p += __shfl_xor(p, 2, 32);
        p += __shfl_xor(p, 1, 32);
        sc[j] = p * scale;
    }
    float m = sc[0];
    #pragma unroll
    for (int j = 1; j < KS; ++j) m = fmaxf(m, sc[j]);
    float l = 0.f, o = 0.f;
    #pragma unroll
    for (int j = 0; j < KS; ++j) {
        const float a = __expf(sc[j] - m);
        l += a;
        o += a * vv[j];
    }
    ctx[(size_t)node * 128 + t] = o / l;
}

// ---------------------------------------------------------------------------
// out = LayerNorm(a + b) * g + be ; one wave per row, 2 elems per lane.
// ---------------------------------------------------------------------------
__global__ __launch_bounds__(256) void resln_kernel(
    const float* __restrict__ a, const float* __restrict__ b,
    const float* __restrict__ g, const float* __restrict__ be,
    float* __restrict__ out, int n)
{
    const int row = (blockIdx.x * 256 + threadIdx.x) >> 6;
    const int lane = threadIdx.x & 63;
    if (row >= n) return;
    const size_t base = (size_t)row * 128;
    float v0 = a[base + lane] + b[base + lane];
    float v1 = a[base + 64 + lane] + b[base + 64 + lane];
    float s = v0 + v1;
    #pragma unroll
    for (int m = 32; m >= 1; m >>= 1) s += __shfl_xor(s, m, 64);
    const float mean = s * (1.f / 128.f);
    const float d0 = v0 - mean, d1 = v1 - mean;
    float vs = d0 * d0 + d1 * d1;
    #pragma unroll
    for (int m = 32; m >= 1; m >>= 1) vs += __shfl_xor(vs, m, 64);
    const float rstd = rsqrtf(vs * (1.f / 128.f) + 1e-5f);
    out[base + lane]      = d0 * rstd * g[lane]      + be[lane];
    out[base + 64 + lane] = d1 * rstd * g[lane + 64] + be[lane + 64];
}

// ---------------------------------------------------------------------------
// CSR build (keyed by edge_src) + aggregation (sum of h[dst] per src).
// ---------------------------------------------------------------------------
__global__ void count_kernel(const int* __restrict__ src, int* __restrict__ deg, int E)
{
    const int e = blockIdx.x * 256 + threadIdx.x;
    if (e < E) atomicAdd(&deg[src[e]], 1);
}

__global__ __launch_bounds__(1024) void scan_kernel(
    const int* __restrict__ deg, int* __restrict__ offs, int n)
{
    __shared__ int buf[1024];
    __shared__ int carry_s;
    const int tid = threadIdx.x;
    if (tid == 0) carry_s = 0;
    __syncthreads();
    for (int base = 0; base < n; base += 1024) {
        const int i = base + tid;
        const int v = (i < n) ? deg[i] : 0;
        buf[tid] = v;
        __syncthreads();
        for (int off = 1; off < 1024; off <<= 1) {
            const int t = (tid >= off) ? buf[tid - off] : 0;
            __syncthreads();
            buf[tid] += t;
            __syncthreads();
        }
        const int incl = buf[tid];
        const int carry = carry_s;
        if (i < n) offs[i] = carry + incl - v;   // exclusive
        __syncthreads();
        if (tid == 1023) carry_s = carry + incl;
        __syncthreads();
    }
}

__global__ void fill_kernel(const int* __restrict__ src, const int* __restrict__ dst,
                            const int* __restrict__ offs, int* __restrict__ cursor,
                            int* __restrict__ csr, int E)
{
    const int e = blockIdx.x * 256 + threadIdx.x;
    if (e < E) {
        const int s = src[e];
        const int pos = atomicAdd(&cursor[s], 1);
        csr[offs[s] + pos] = dst[e];
    }
}

__global__ __launch_bounds__(256) void aggregate_kernel(
    const float* __restrict__ h, const int* __restrict__ offs,
    const int* __restrict__ csr, float* __restrict__ outp, int n, int E)
{
    const int node = blockIdx.x * 2 + (threadIdx.x >> 7);
    const int t = threadIdx.x & 127;
    if (node >= n) return;
    const int s = offs[node];
    const int e = (node == n - 1) ? E : offs[node + 1];
    float acc = 0.f;
    for (int i = s; i < e; ++i) {
        const int d = csr[i];
        acc += h[(size_t)d * 128 + t];
    }
    outp[(size_t)node * 128 + t] = acc;
}

// ---------------------------------------------------------------------------
extern "C" void kernel_launch(void* const* d_in, const int* in_sizes, int n_in,
                              void* d_out, int out_size, void* d_ws, size_t ws_size,
                              hipStream_t stream)
{
    const float* x        = (const float*)d_in[0];
    const int*   samples  = (const int*)d_in[1];
    const int*   esrc     = (const int*)d_in[2];
    const int*   edst     = (const int*)d_in[3];
    const float* t_in_w   = (const float*)d_in[4];   // [3][384][128]
    const float* t_in_b   = (const float*)d_in[5];   // [3][384]
    const float* t_out_w  = (const float*)d_in[6];   // [3][128][128]
    const float* t_out_b  = (const float*)d_in[7];   // [3][128]
    const float* t_ffn_w1 = (const float*)d_in[8];   // [3][512][128]
    const float* t_ffn_b1 = (const float*)d_in[9];   // [3][512]
    const float* t_ffn_w2 = (const float*)d_in[10];  // [3][128][512]
    const float* t_ffn_b2 = (const float*)d_in[11];  // [3][128]
    const float* t_ln1_g  = (const float*)d_in[12];
    const float* t_ln1_b  = (const float*)d_in[13];
    const float* t_ln2_g  = (const float*)d_in[14];
    const float* t_ln2_b  = (const float*)d_in[15];
    const float* g_w      = (const float*)d_in[16];  // [2][128][256]
    const float* g_b      = (const float*)d_in[17];  // [2][128]
    const float* g_ln_g   = (const float*)d_in[18];
    const float* g_ln_b   = (const float*)d_in[19];

    const int N = in_sizes[0] / DM;
    const int E = in_sizes[2];

    float* h = (float*)d_out;                // [N][128] working hidden state

    float* A  = (float*)d_ws;                // [N][512]  (QKV re-used as FFN hidden)
    float* B  = A + (size_t)N * 512;         // [N][128]  (attn ctx / gnn neigh)
    float* C  = B + (size_t)N * 128;         // [N][128]  (pre-LN branch output)
    int* offs   = (int*)(C + (size_t)N * 128);  // [N]
    int* cursor = offs + N;                     // [N] (also degree histogram)
    int* csr    = cursor + N;                   // [E]

    const int mt = (N + 63) / 64;            // GEMM row tiles
    const dim3 blk(256);

    // h = x
    hipMemcpyAsync(h, x, (size_t)N * DM * sizeof(float), hipMemcpyDeviceToDevice, stream);

    // ---- build CSR once (same edges for both GNN layers) ----
    hipMemsetAsync(cursor, 0, N * sizeof(int), stream);
    count_kernel<<<(E + 255) / 256, blk, 0, stream>>>(esrc, cursor, E);
    scan_kernel<<<1, 1024, 0, stream>>>(cursor, offs, N);
    hipMemsetAsync(cursor, 0, N * sizeof(int), stream);
    fill_kernel<<<(E + 255) / 256, blk, 0, stream>>>(esrc, edst, offs, cursor, csr, E);

    const int ln_grid = (N + 3) / 4;
    const int attn_grid = (N + 1) / 2;

    for (int layer = 0; layer < 5; ++layer) {
        if (layer == 1 || layer == 3) {
            // ---------------- GNN block ----------------
            const int i = (layer == 1) ? 0 : 1;
            aggregate_kernel<<<attn_grid, blk, 0, stream>>>(h, offs, csr, B, N, E);
            gemm_kernel<256, 128, true, 128><<<dim3(mt, 2), blk, 0, stream>>>(
                h, B, g_w + (size_t)i * 128 * 256, g_b + i * 128, C, N);
            resln_kernel<<<ln_grid, blk, 0, stream>>>(
                h, C, g_ln_g + i * 128, g_ln_b + i * 128, h, N);
        } else {
            // ---------------- Transformer block ----------------
            const int i = (layer == 0) ? 0 : (layer == 2 ? 1 : 2);
            // QKV = h @ in_w^T + in_b   (project THEN gather: exact rewrite)
            gemm_kernel<128, 384, false, 0><<<dim3(mt, 6), blk, 0, stream>>>(
                h, nullptr, t_in_w + (size_t)i * 384 * 128, t_in_b + i * 384, A, N);
            attn_kernel<<<attn_grid, blk, 0, stream>>>(A, samples, B, N);
            gemm_kernel<128, 128, false, 0><<<dim3(mt, 2), blk, 0, stream>>>(
                B, nullptr, t_out_w + (size_t)i * 128 * 128, t_out_b + i * 128, C, N);
            resln_kernel<<<ln_grid, blk, 0, stream>>>(
                h, C, t_ln1_g + i * 128, t_ln1_b + i * 128, h, N);
            gemm_kernel<128, 512, true, 0><<<dim3(mt, 8), blk, 0, stream>>>(
                h, nullptr, t_ffn_w1 + (size_t)i * 512 * 128, t_ffn_b1 + i * 512, A, N);
            gemm_kernel<512, 128, false, 0><<<dim3(mt, 2), blk, 0, stream>>>(
                A, nullptr, t_ffn_w2 + (size_t)i * 128 * 512, t_ffn_b2 + i * 128, C, N);
            resln_kernel<<<ln_grid, blk, 0, stream>>>(
                h, C, t_ln2_g + i * 128, t_ln2_b + i * 128, h, N);
        }
    }
}

// Round 2
// 1539.082 us; speedup vs baseline: 1.5760x; 1.5760x over previous
//
#include <hip/hip_runtime.h>

#define DM 128          // model dim
#define KS 20           // attention samples

typedef __attribute__((ext_vector_type(8))) short short8;   // 8 bf16 (4 VGPRs)
typedef __attribute__((ext_vector_type(4))) float f32x4;

__device__ __forceinline__ unsigned short f2b(float f) {
    unsigned u = __float_as_uint(f);
    u += 0x7fff + ((u >> 16) & 1);          // RNE
    return (unsigned short)(u >> 16);
}
__device__ __forceinline__ float b2f(unsigned short b) {
    return __uint_as_float(((unsigned)b) << 16);
}

// ---------------------------------------------------------------------------
// fp32 -> bf16 bulk convert
// ---------------------------------------------------------------------------
__global__ void cvt_kernel(const float* __restrict__ src, unsigned short* __restrict__ dst, int n)
{
    const int i = blockIdx.x * 256 + threadIdx.x;
    if (i < n) dst[i] = f2b(src[i]);
}

// ---------------------------------------------------------------------------
// MFMA GEMM: out[M][CO] = X[M][CI](bf16) @ W[CO][CI](bf16)^T + bias, opt ReLU.
// SPLIT>0: X cols [0,SPLIT) from X0 (stride SPLIT), rest from X1.
// Block 64x64 (256 thr = 4 waves, each wave 32x32 via 2x2 mfma_16x16x32_bf16).
// A-frag: lane m=lane&15, k=quad*8+j ; B-frag: lane n=lane&15, k=quad*8+j.
// C/D:    col=lane&15, row=quad*4+reg.
// ---------------------------------------------------------------------------
template <int CI, int CO, bool RELU, int SPLIT, bool OUTBF>
__global__ __launch_bounds__(256) void gemm_mfma(
    const unsigned short* __restrict__ X0, const unsigned short* __restrict__ X1,
    const unsigned short* __restrict__ W, const float* __restrict__ bias,
    float* __restrict__ outF, unsigned short* __restrict__ outB, int M)
{
    const int tid  = threadIdx.x;
    const int wave = tid >> 6;
    const int lane = tid & 63;
    const int m0 = blockIdx.x * 64 + (wave >> 1) * 32;
    const int c0 = blockIdx.y * 64 + (wave & 1) * 32;
    const int lrow = lane & 15;
    const int quad = lane >> 4;

    f32x4 acc[2][2];
    #pragma unroll
    for (int i = 0; i < 2; ++i)
        #pragma unroll
        for (int j = 0; j < 2; ++j)
            acc[i][j] = (f32x4){0.f, 0.f, 0.f, 0.f};

    const int r0 = m0 + lrow;
    const int r1 = m0 + 16 + lrow;
    const bool v0 = r0 < M, v1 = r1 < M;

    #pragma unroll
    for (int k0 = 0; k0 < CI; k0 += 32) {
        const unsigned short* xs;
        int kk, stride;
        if (SPLIT > 0 && k0 >= SPLIT) { xs = X1; kk = k0 - SPLIT; stride = CI - SPLIT; }
        else                          { xs = X0; kk = k0;         stride = (SPLIT > 0) ? SPLIT : CI; }
        const int ko = kk + quad * 8;
        short8 a0 = {}, a1 = {};
        if (v0) a0 = *(const short8*)(xs + (size_t)r0 * stride + ko);
        if (v1) a1 = *(const short8*)(xs + (size_t)r1 * stride + ko);
        const int kw = k0 + quad * 8;
        const short8 b0 = *(const short8*)(W + (size_t)(c0 + lrow) * CI + kw);
        const short8 b1 = *(const short8*)(W + (size_t)(c0 + 16 + lrow) * CI + kw);
        acc[0][0] = __builtin_amdgcn_mfma_f32_16x16x32_bf16(a0, b0, acc[0][0], 0, 0, 0);
        acc[0][1] = __builtin_amdgcn_mfma_f32_16x16x32_bf16(a0, b1, acc[0][1], 0, 0, 0);
        acc[1][0] = __builtin_amdgcn_mfma_f32_16x16x32_bf16(a1, b0, acc[1][0], 0, 0, 0);
        acc[1][1] = __builtin_amdgcn_mfma_f32_16x16x32_bf16(a1, b1, acc[1][1], 0, 0, 0);
    }

    #pragma unroll
    for (int i = 0; i < 2; ++i) {
        const int rb = m0 + i * 16 + quad * 4;
        #pragma unroll
        for (int j = 0; j < 2; ++j) {
            const int col = c0 + j * 16 + lrow;
            const float bsv = bias[col];
            #pragma unroll
            for (int r = 0; r < 4; ++r) {
                const int row = rb + r;
                if (row < M) {
                    float v = acc[i][j][r] + bsv;
                    if (RELU) v = fmaxf(v, 0.f);
                    if (OUTBF) outB[(size_t)row * CO + col] = f2b(v);
                    else       outF[(size_t)row * CO + col] = v;
                }
            }
        }
    }
}

// ---------------------------------------------------------------------------
// Fused sampled attention (bf16 QKV in, bf16 ctx out). 128 thr/node.
// ---------------------------------------------------------------------------
__global__ __launch_bounds__(256) void attn_kernel(
    const unsigned short* __restrict__ qkv, const int* __restrict__ samples,
    unsigned short* __restrict__ ctx, int n)
{
    const int node = blockIdx.x * 2 + (threadIdx.x >> 7);
    const int t = threadIdx.x & 127;
    if (node >= n) return;

    const float scale = 0.17677669529663687f;  // 1/sqrt(32)
    const float qv = b2f(qkv[(size_t)node * 384 + t]);

    float sc[KS], vv[KS];
    #pragma unroll
    for (int j = 0; j < KS; ++j) {
        const int row = samples[node * KS + j];
        const size_t base = (size_t)row * 384;
        const float kv = b2f(qkv[base + 128 + t]);
        vv[j] = b2f(qkv[base + 256 + t]);
        float p = qv * kv;
        p += __shfl_xor(p, 16, 32);
        p += __shfl_xor(p, 8, 32);
        p += __shfl_xor(p, 4, 32);
        p += __shfl_xor(p, 2, 32);
        p += __shfl_xor(p, 1, 32);
        sc[j] = p * scale;
    }
    float m = sc[0];
    #pragma unroll
    for (int j = 1; j < KS; ++j) m = fmaxf(m, sc[j]);
    float l = 0.f, o = 0.f;
    #pragma unroll
    for (int j = 0; j < KS; ++j) {
        const float a = __expf(sc[j] - m);
        l += a;
        o += a * vv[j];
    }
    ctx[(size_t)node * 128 + t] = f2b(o / l);
}

// ---------------------------------------------------------------------------
// out = LayerNorm(a + b) * g + be ; writes fp32 (residual chain) + bf16 copy.
// ---------------------------------------------------------------------------
__global__ __launch_bounds__(256) void resln_kernel(
    const float* __restrict__ a, const float* __restrict__ b,
    const float* __restrict__ g, const float* __restrict__ be,
    float* __restrict__ outF, unsigned short* __restrict__ outB, int n)
{
    const int row = (blockIdx.x * 256 + threadIdx.x) >> 6;
    const int lane = threadIdx.x & 63;
    if (row >= n) return;
    const size_t base = (size_t)row * 128;
    float v0 = a[base + lane] + b[base + lane];
    float v1 = a[base + 64 + lane] + b[base + 64 + lane];
    float s = v0 + v1;
    #pragma unroll
    for (int m = 32; m >= 1; m >>= 1) s += __shfl_xor(s, m, 64);
    const float mean = s * (1.f / 128.f);
    const float d0 = v0 - mean, d1 = v1 - mean;
    float vs = d0 * d0 + d1 * d1;
    #pragma unroll
    for (int m = 32; m >= 1; m >>= 1) vs += __shfl_xor(vs, m, 64);
    const float rstd = rsqrtf(vs * (1.f / 128.f) + 1e-5f);
    const float o0 = d0 * rstd * g[lane]      + be[lane];
    const float o1 = d1 * rstd * g[lane + 64] + be[lane + 64];
    outF[base + lane]      = o0;
    outF[base + 64 + lane] = o1;
    outB[base + lane]      = f2b(o0);
    outB[base + 64 + lane] = f2b(o1);
}

// ---------------------------------------------------------------------------
// CSR build (keyed by edge_src) + bf16 aggregation (sum of h[dst] per src).
// ---------------------------------------------------------------------------
__global__ void count_kernel(const int* __restrict__ src, int* __restrict__ deg, int E)
{
    const int e = blockIdx.x * 256 + threadIdx.x;
    if (e < E) atomicAdd(&deg[src[e]], 1);
}

__global__ __launch_bounds__(1024) void scan_kernel(
    const int* __restrict__ deg, int* __restrict__ offs, int n)
{
    __shared__ int buf[1024];
    __shared__ int carry_s;
    const int tid = threadIdx.x;
    if (tid == 0) carry_s = 0;
    __syncthreads();
    for (int base = 0; base < n; base += 1024) {
        const int i = base + tid;
        const int v = (i < n) ? deg[i] : 0;
        buf[tid] = v;
        __syncthreads();
        for (int off = 1; off < 1024; off <<= 1) {
            const int t = (tid >= off) ? buf[tid - off] : 0;
            __syncthreads();
            buf[tid] += t;
            __syncthreads();
        }
        const int incl = buf[tid];
        const int carry = carry_s;
        if (i < n) offs[i] = carry + incl - v;   // exclusive
        __syncthreads();
        if (tid == 1023) carry_s = carry + incl;
        __syncthreads();
    }
}

__global__ void fill_kernel(const int* __restrict__ src, const int* __restrict__ dst,
                            const int* __restrict__ offs, int* __restrict__ cursor,
                            int* __restrict__ csr, int E)
{
    const int e = blockIdx.x * 256 + threadIdx.x;
    if (e < E) {
        const int s = src[e];
        const int pos = atomicAdd(&cursor[s], 1);
        csr[offs[s] + pos] = dst[e];
    }
}

// one wave per node, ushort2 per lane, edge loop unrolled x4 for MLP
__global__ __launch_bounds__(256) void aggregate_kernel(
    const unsigned short* __restrict__ hb, const int* __restrict__ offs,
    const int* __restrict__ csr, unsigned short* __restrict__ outp, int n, int E)
{
    const int node = blockIdx.x * 4 + (threadIdx.x >> 6);
    const int lane = threadIdx.x & 63;
    if (node >= n) return;
    const int s = offs[node];
    const int e = (node == n - 1) ? E : offs[node + 1];
    float a0 = 0.f, a1 = 0.f;
    int i = s;
    for (; i + 4 <= e; i += 4) {
        const int d0 = csr[i], d1 = csr[i + 1], d2 = csr[i + 2], d3 = csr[i + 3];
        const unsigned u0 = *(const unsigned*)(hb + (size_t)d0 * 128 + lane * 2);
        const unsigned u1 = *(const unsigned*)(hb + (size_t)d1 * 128 + lane * 2);
        const unsigned u2 = *(const unsigned*)(hb + (size_t)d2 * 128 + lane * 2);
        const unsigned u3 = *(const unsigned*)(hb + (size_t)d3 * 128 + lane * 2);
        a0 += b2f((unsigned short)u0) + b2f((unsigned short)u1)
            + b2f((unsigned short)u2) + b2f((unsigned short)u3);
        a1 += b2f((unsigned short)(u0 >> 16)) + b2f((unsigned short)(u1 >> 16))
            + b2f((unsigned short)(u2 >> 16)) + b2f((unsigned short)(u3 >> 16));
    }
    for (; i < e; ++i) {
        const unsigned u = *(const unsigned*)(hb + (size_t)csr[i] * 128 + lane * 2);
        a0 += b2f((unsigned short)u);
        a1 += b2f((unsigned short)(u >> 16));
    }
    const unsigned ow = (unsigned)f2b(a0) | ((unsigned)f2b(a1) << 16);
    *(unsigned*)(outp + (size_t)node * 128 + lane * 2) = ow;
}

// ---------------------------------------------------------------------------
extern "C" void kernel_launch(void* const* d_in, const int* in_sizes, int n_in,
                              void* d_out, int out_size, void* d_ws, size_t ws_size,
                              hipStream_t stream)
{
    const float* x        = (const float*)d_in[0];
    const int*   samples  = (const int*)d_in[1];
    const int*   esrc     = (const int*)d_in[2];
    const int*   edst     = (const int*)d_in[3];
    const float* t_in_w   = (const float*)d_in[4];   // [3][384][128]
    const float* t_in_b   = (const float*)d_in[5];
    const float* t_out_w  = (const float*)d_in[6];   // [3][128][128]
    const float* t_out_b  = (const float*)d_in[7];
    const float* t_ffn_w1 = (const float*)d_in[8];   // [3][512][128]
    const float* t_ffn_b1 = (const float*)d_in[9];
    const float* t_ffn_w2 = (const float*)d_in[10];  // [3][128][512]
    const float* t_ffn_b2 = (const float*)d_in[11];
    const float* t_ln1_g  = (const float*)d_in[12];
    const float* t_ln1_b  = (const float*)d_in[13];
    const float* t_ln2_g  = (const float*)d_in[14];
    const float* t_ln2_b  = (const float*)d_in[15];
    const float* g_w      = (const float*)d_in[16];  // [2][128][256]
    const float* g_b      = (const float*)d_in[17];
    const float* g_ln_g   = (const float*)d_in[18];
    const float* g_ln_b   = (const float*)d_in[19];

    const int N = in_sizes[0] / DM;
    const int E = in_sizes[2];

    float* h = (float*)d_out;                        // [N][128] fp32 hidden

    // ---- workspace layout ----
    unsigned short* wbuf = (unsigned short*)d_ws;    // bf16 weights
    unsigned short* w_in  = wbuf;                    // 3*384*128 = 147456
    unsigned short* w_out = w_in  + 147456;          // 3*128*128 = 49152
    unsigned short* w_f1  = w_out + 49152;           // 3*512*128 = 196608
    unsigned short* w_f2  = w_f1  + 196608;          // 3*128*512 = 196608
    unsigned short* w_g   = w_f2  + 196608;          // 2*128*256 = 65536
    unsigned short* hb    = w_g   + 65536;           // [N][128] bf16 hidden
    unsigned short* Abf   = hb  + (size_t)N * 128;   // [N][512] QKV / FFN hidden
    unsigned short* Bbf   = Abf + (size_t)N * 512;   // [N][128] ctx / neigh
    float* C   = (float*)(Bbf + (size_t)N * 128);    // [N][128] fp32 branch out
    int* offs   = (int*)(C + (size_t)N * 128);
    int* cursor = offs + N;
    int* csr    = cursor + N;

    const int mt = (N + 63) / 64;
    const dim3 blk(256);

    // h = x (fp32) ; hb = bf16(x)
    hipMemcpyAsync(h, x, (size_t)N * DM * sizeof(float), hipMemcpyDeviceToDevice, stream);
    cvt_kernel<<<((N * DM) + 255) / 256, blk, 0, stream>>>(x, hb, N * DM);

    // ---- convert weights to bf16 (once per call) ----
    cvt_kernel<<<(147456 + 255) / 256, blk, 0, stream>>>(t_in_w,   w_in,  147456);
    cvt_kernel<<<(49152  + 255) / 256, blk, 0, stream>>>(t_out_w,  w_out, 49152);
    cvt_kernel<<<(196608 + 255) / 256, blk, 0, stream>>>(t_ffn_w1, w_f1,  196608);
    cvt_kernel<<<(196608 + 255) / 256, blk, 0, stream>>>(t_ffn_w2, w_f2,  196608);
    cvt_kernel<<<(65536  + 255) / 256, blk, 0, stream>>>(g_w,      w_g,   65536);

    // ---- build CSR once ----
    hipMemsetAsync(cursor, 0, N * sizeof(int), stream);
    count_kernel<<<(E + 255) / 256, blk, 0, stream>>>(esrc, cursor, E);
    scan_kernel<<<1, 1024, 0, stream>>>(cursor, offs, N);
    hipMemsetAsync(cursor, 0, N * sizeof(int), stream);
    fill_kernel<<<(E + 255) / 256, blk, 0, stream>>>(esrc, edst, offs, cursor, csr, E);

    const int ln_grid = (N + 3) / 4;
    const int attn_grid = (N + 1) / 2;
    const int agg_grid = (N + 3) / 4;

    for (int layer = 0; layer < 5; ++layer) {
        if (layer == 1 || layer == 3) {
            // ---------------- GNN block ----------------
            const int i = (layer == 1) ? 0 : 1;
            aggregate_kernel<<<agg_grid, blk, 0, stream>>>(hb, offs, csr, Bbf, N, E);
            gemm_mfma<256, 128, true, 128, false><<<dim3(mt, 2), blk, 0, stream>>>(
                hb, Bbf, w_g + (size_t)i * 32768, g_b + i * 128, C, nullptr, N);
            resln_kernel<<<ln_grid, blk, 0, stream>>>(
                h, C, g_ln_g + i * 128, g_ln_b + i * 128, h, hb, N);
        } else {
            // ---------------- Transformer block ----------------
            const int i = (layer == 0) ? 0 : (layer == 2 ? 1 : 2);
            // QKV = h @ in_w^T + in_b (project THEN gather) -> bf16
            gemm_mfma<128, 384, false, 0, true><<<dim3(mt, 6), blk, 0, stream>>>(
                hb, nullptr, w_in + (size_t)i * 49152, t_in_b + i * 384, nullptr, Abf, N);
            attn_kernel<<<attn_grid, blk, 0, stream>>>(Abf, samples, Bbf, N);
            gemm_mfma<128, 128, false, 0, false><<<dim3(mt, 2), blk, 0, stream>>>(
                Bbf, nullptr, w_out + (size_t)i * 16384, t_out_b + i * 128, C, nullptr, N);
            resln_kernel<<<ln_grid, blk, 0, stream>>>(
                h, C, t_ln1_g + i * 128, t_ln1_b + i * 128, h, hb, N);
            gemm_mfma<128, 512, true, 0, true><<<dim3(mt, 8), blk, 0, stream>>>(
                hb, nullptr, w_f1 + (size_t)i * 65536, t_ffn_b1 + i * 512, nullptr, Abf, N);
            gemm_mfma<512, 128, false, 0, false><<<dim3(mt, 2), blk, 0, stream>>>(
                Abf, nullptr, w_f2 + (size_t)i * 65536, t_ffn_b2 + i * 128, C, nullptr, N);
            resln_kernel<<<ln_grid, blk, 0, stream>>>(
                h, C, t_ln2_g + i * 128, t_ln2_b + i * 128, h, hb, N);
        }
    }
}

// Round 3
// 1340.833 us; speedup vs baseline: 1.8090x; 1.1479x over previous
//
#include <hip/hip_runtime.h>

#define DM 128          // model dim
#define KS 20           // attention samples

typedef __attribute__((ext_vector_type(8))) short short8;   // 8 bf16 (4 VGPRs)
typedef __attribute__((ext_vector_type(4))) float f32x4;

__device__ __forceinline__ unsigned short f2b(float f) {
    unsigned u = __float_as_uint(f);
    u += 0x7fff + ((u >> 16) & 1);          // RNE
    return (unsigned short)(u >> 16);
}
__device__ __forceinline__ float b2f(unsigned short b) {
    return __uint_as_float(((unsigned)b) << 16);
}
__device__ __forceinline__ float blo(unsigned u) { return __uint_as_float(u << 16); }
__device__ __forceinline__ float bhi(unsigned u) { return __uint_as_float(u & 0xffff0000u); }
__device__ __forceinline__ unsigned pk(float a, float b) {
    return (unsigned)f2b(a) | ((unsigned)f2b(b) << 16);
}

// ---------------------------------------------------------------------------
// fp32 -> bf16 bulk convert, float4 wide (n % 4 == 0 for all users)
// ---------------------------------------------------------------------------
__global__ void cvt_kernel(const float* __restrict__ src, unsigned short* __restrict__ dst, int n)
{
    const int i = (blockIdx.x * 256 + threadIdx.x) * 4;
    if (i < n) {
        const float4 v = *(const float4*)(src + i);
        ((unsigned*)dst)[i / 2]     = pk(v.x, v.y);
        ((unsigned*)dst)[i / 2 + 1] = pk(v.z, v.w);
    }
}

// ---------------------------------------------------------------------------
// Plain MFMA GEMM (bf16 out): out = X@W^T + bias, opt ReLU. Block 64x64.
// A-frag: m=lane&15, k=quad*8+j ; C/D: col=lane&15, row=quad*4+reg. (verified R2)
// ---------------------------------------------------------------------------
template <int CI, int CO, bool RELU>
__global__ __launch_bounds__(256) void gemm_mfma(
    const unsigned short* __restrict__ X,
    const unsigned short* __restrict__ W, const float* __restrict__ bias,
    unsigned short* __restrict__ outB, int M)
{
    const int tid  = threadIdx.x;
    const int wave = tid >> 6;
    const int lane = tid & 63;
    const int m0 = blockIdx.x * 64 + (wave >> 1) * 32;
    const int c0 = blockIdx.y * 64 + (wave & 1) * 32;
    const int lrow = lane & 15;
    const int quad = lane >> 4;

    f32x4 acc[2][2];
    #pragma unroll
    for (int i = 0; i < 2; ++i)
        #pragma unroll
        for (int j = 0; j < 2; ++j)
            acc[i][j] = (f32x4){0.f, 0.f, 0.f, 0.f};

    const int r0 = m0 + lrow;
    const int r1 = m0 + 16 + lrow;
    const bool v0 = r0 < M, v1 = r1 < M;

    #pragma unroll
    for (int k0 = 0; k0 < CI; k0 += 32) {
        const int ko = k0 + quad * 8;
        short8 a0 = {}, a1 = {};
        if (v0) a0 = *(const short8*)(X + (size_t)r0 * CI + ko);
        if (v1) a1 = *(const short8*)(X + (size_t)r1 * CI + ko);
        const short8 b0 = *(const short8*)(W + (size_t)(c0 + lrow) * CI + ko);
        const short8 b1 = *(const short8*)(W + (size_t)(c0 + 16 + lrow) * CI + ko);
        acc[0][0] = __builtin_amdgcn_mfma_f32_16x16x32_bf16(a0, b0, acc[0][0], 0, 0, 0);
        acc[0][1] = __builtin_amdgcn_mfma_f32_16x16x32_bf16(a0, b1, acc[0][1], 0, 0, 0);
        acc[1][0] = __builtin_amdgcn_mfma_f32_16x16x32_bf16(a1, b0, acc[1][0], 0, 0, 0);
        acc[1][1] = __builtin_amdgcn_mfma_f32_16x16x32_bf16(a1, b1, acc[1][1], 0, 0, 0);
    }

    #pragma unroll
    for (int i = 0; i < 2; ++i) {
        const int rb = m0 + i * 16 + quad * 4;
        #pragma unroll
        for (int j = 0; j < 2; ++j) {
            const int col = c0 + j * 16 + lrow;
            const float bsv = bias[col];
            #pragma unroll
            for (int r = 0; r < 4; ++r) {
                const int row = rb + r;
                if (row < M) {
                    float v = acc[i][j][r] + bsv;
                    if (RELU) v = fmaxf(v, 0.f);
                    outB[(size_t)row * CO + col] = f2b(v);
                }
            }
        }
    }
}

// ---------------------------------------------------------------------------
// Fused GEMM(CO=128) + residual + LayerNorm.
//   Y = X@W^T + bias ; if RELU: Y=relu(Y) ; out = LN(Y + resid)*g + be
// Block = 64 rows x 128 cols (full row in-block => LN stats via LDS).
// 4 waves in 2x2: wave row covers 32 rows, wave col covers 64 cols (2x4 mfma).
// Writes fp32 hF and bf16 hB.
// ---------------------------------------------------------------------------
template <int CI, bool RELU, int SPLIT>
__global__ __launch_bounds__(256) void gemm_ln(
    const unsigned short* __restrict__ X0, const unsigned short* __restrict__ X1,
    const unsigned short* __restrict__ W, const float* __restrict__ bias,
    const float* __restrict__ resid,
    const float* __restrict__ g, const float* __restrict__ be,
    float* __restrict__ hF, unsigned short* __restrict__ hB, int M)
{
    __shared__ float psum[64][2][2];   // [row][wave-col][{sum,sumsq}]
    __shared__ float stats[64][2];     // [row][{mean,rstd}]

    const int tid  = threadIdx.x;
    const int wave = tid >> 6;
    const int lane = tid & 63;
    const int wr = (wave >> 1) * 32;           // wave row offset in block
    const int wc = wave & 1;                   // wave col half
    const int m0 = blockIdx.x * 64 + wr;
    const int c0 = wc * 64;
    const int lrow = lane & 15;
    const int quad = lane >> 4;

    f32x4 acc[2][4];
    #pragma unroll
    for (int i = 0; i < 2; ++i)
        #pragma unroll
        for (int j = 0; j < 4; ++j)
            acc[i][j] = (f32x4){0.f, 0.f, 0.f, 0.f};

    const int r0 = m0 + lrow;
    const int r1 = m0 + 16 + lrow;
    const bool v0 = r0 < M, v1 = r1 < M;

    for (int k0 = 0; k0 < CI; k0 += 32) {
        const unsigned short* xs;
        int kk, stride;
        if (SPLIT > 0 && k0 >= SPLIT) { xs = X1; kk = k0 - SPLIT; stride = CI - SPLIT; }
        else                          { xs = X0; kk = k0;         stride = (SPLIT > 0) ? SPLIT : CI; }
        const int ko = kk + quad * 8;
        short8 a0 = {}, a1 = {};
        if (v0) a0 = *(const short8*)(xs + (size_t)r0 * stride + ko);
        if (v1) a1 = *(const short8*)(xs + (size_t)r1 * stride + ko);
        const int kw = k0 + quad * 8;
        #pragma unroll
        for (int j = 0; j < 4; ++j) {
            const short8 bf = *(const short8*)(W + (size_t)(c0 + j * 16 + lrow) * CI + kw);
            acc[0][j] = __builtin_amdgcn_mfma_f32_16x16x32_bf16(a0, bf, acc[0][j], 0, 0, 0);
            acc[1][j] = __builtin_amdgcn_mfma_f32_16x16x32_bf16(a1, bf, acc[1][j], 0, 0, 0);
        }
    }

    // per-column constants for this lane
    float bcol[4], gcol[4], bec[4];
    #pragma unroll
    for (int j = 0; j < 4; ++j) {
        const int col = c0 + j * 16 + lrow;
        bcol[j] = bias[col];
        gcol[j] = g[col];
        bec[j]  = be[col];
    }

    // bias + relu + residual; per-row partial sums -> LDS
    float vals[2][4][4];
    #pragma unroll
    for (int i = 0; i < 2; ++i) {
        #pragma unroll
        for (int r = 0; r < 4; ++r) {
            const int lrel = wr + i * 16 + quad * 4 + r;
            const int row = blockIdx.x * 64 + lrel;
            const bool vr = row < M;
            float s = 0.f, s2 = 0.f;
            #pragma unroll
            for (int j = 0; j < 4; ++j) {
                const int col = c0 + j * 16 + lrow;
                float v = acc[i][j][r] + bcol[j];
                if (RELU) v = fmaxf(v, 0.f);
                if (vr) v += resid[(size_t)row * 128 + col];
                vals[i][j][r] = v;
                s += v; s2 += v * v;
            }
            s  += __shfl_xor(s, 1);  s  += __shfl_xor(s, 2);
            s  += __shfl_xor(s, 4);  s  += __shfl_xor(s, 8);
            s2 += __shfl_xor(s2, 1); s2 += __shfl_xor(s2, 2);
            s2 += __shfl_xor(s2, 4); s2 += __shfl_xor(s2, 8);
            if (lrow == 0) { psum[lrel][wc][0] = s; psum[lrel][wc][1] = s2; }
        }
    }
    __syncthreads();
    if (tid < 64) {
        const float sum   = psum[tid][0][0] + psum[tid][1][0];
        const float sumsq = psum[tid][0][1] + psum[tid][1][1];
        const float mean = sum * (1.f / 128.f);
        const float var  = sumsq * (1.f / 128.f) - mean * mean;
        stats[tid][0] = mean;
        stats[tid][1] = rsqrtf(var + 1e-5f);
    }
    __syncthreads();

    #pragma unroll
    for (int i = 0; i < 2; ++i) {
        #pragma unroll
        for (int r = 0; r < 4; ++r) {
            const int lrel = wr + i * 16 + quad * 4 + r;
            const int row = blockIdx.x * 64 + lrel;
            if (row < M) {
                const float mean = stats[lrel][0];
                const float rstd = stats[lrel][1];
                #pragma unroll
                for (int j = 0; j < 4; ++j) {
                    const int col = c0 + j * 16 + lrow;
                    const float o = (vals[i][j][r] - mean) * rstd * gcol[j] + bec[j];
                    hF[(size_t)row * 128 + col] = o;
                    hB[(size_t)row * 128 + col] = f2b(o);
                }
            }
        }
    }
}

// ---------------------------------------------------------------------------
// Fused sampled attention, wave per node. lane = s4*16 + p.
// slot s4 in [0,4): sample in flight; p in [0,16): dims [8p,8p+8).
// Head = p>>2 ; head-group dot reduce via shfl_xor 1,2 ; cross-slot via 16,32.
// ---------------------------------------------------------------------------
__global__ __launch_bounds__(256) void attn_kernel(
    const unsigned short* __restrict__ qkv, const int* __restrict__ samples,
    unsigned short* __restrict__ ctx, int n)
{
    const int node = blockIdx.x * 4 + (threadIdx.x >> 6);
    const int lane = threadIdx.x & 63;
    if (node >= n) return;
    const int s4 = lane >> 4;
    const int p  = lane & 15;
    const float scale = 0.17677669529663687f;  // 1/sqrt(32)

    const uint4 qu = *(const uint4*)(qkv + (size_t)node * 384 + p * 8);
    float q[8];
    q[0] = blo(qu.x); q[1] = bhi(qu.x); q[2] = blo(qu.y); q[3] = bhi(qu.y);
    q[4] = blo(qu.z); q[5] = bhi(qu.z); q[6] = blo(qu.w); q[7] = bhi(qu.w);

    float m = -1e30f, l = 0.f;
    float o[8] = {};

    #pragma unroll
    for (int jj = 0; jj < 5; ++jj) {
        const int row = samples[node * KS + jj * 4 + s4];
        const size_t base = (size_t)row * 384 + p * 8;
        const uint4 ku = *(const uint4*)(qkv + base + 128);
        const uint4 vu = *(const uint4*)(qkv + base + 256);
        float d = q[0] * blo(ku.x) + q[1] * bhi(ku.x)
                + q[2] * blo(ku.y) + q[3] * bhi(ku.y)
                + q[4] * blo(ku.z) + q[5] * bhi(ku.z)
                + q[6] * blo(ku.w) + q[7] * bhi(ku.w);
        d += __shfl_xor(d, 1);
        d += __shfl_xor(d, 2);              // head-group (4 lanes) total
        const float sc = d * scale;
        float mx = sc;
        mx = fmaxf(mx, __shfl_xor(mx, 16));
        mx = fmaxf(mx, __shfl_xor(mx, 32)); // cross-slot max (per head)
        const float mnew = fmaxf(m, mx);
        const float corr = __expf(m - mnew);
        const float al   = __expf(sc - mnew);
        l = l * corr + al;
        float v[8];
        v[0] = blo(vu.x); v[1] = bhi(vu.x); v[2] = blo(vu.y); v[3] = bhi(vu.y);
        v[4] = blo(vu.z); v[5] = bhi(vu.z); v[6] = blo(vu.w); v[7] = bhi(vu.w);
        #pragma unroll
        for (int i = 0; i < 8; ++i) o[i] = o[i] * corr + al * v[i];
        m = mnew;
    }

    l += __shfl_xor(l, 16); l += __shfl_xor(l, 32);
    #pragma unroll
    for (int i = 0; i < 8; ++i) {
        o[i] += __shfl_xor(o[i], 16);
        o[i] += __shfl_xor(o[i], 32);
    }
    if (s4 == 0) {
        const float inv = 1.f / l;
        uint4 ow;
        ow.x = pk(o[0] * inv, o[1] * inv);
        ow.y = pk(o[2] * inv, o[3] * inv);
        ow.z = pk(o[4] * inv, o[5] * inv);
        ow.w = pk(o[6] * inv, o[7] * inv);
        *(uint4*)(ctx + (size_t)node * 128 + p * 8) = ow;
    }
}

// ---------------------------------------------------------------------------
// CSR build + aggregation (wave/node, 4 edges in flight, 16B row segments)
// ---------------------------------------------------------------------------
__global__ void count_kernel(const int* __restrict__ src, int* __restrict__ deg, int E)
{
    const int e = blockIdx.x * 256 + threadIdx.x;
    if (e < E) atomicAdd(&deg[src[e]], 1);
}

__global__ __launch_bounds__(1024) void scan1_kernel(
    const int* __restrict__ deg, int* __restrict__ incl, int* __restrict__ btot, int n)
{
    __shared__ int buf[1024];
    const int gid = blockIdx.x * 1024 + threadIdx.x;
    const int v = (gid < n) ? deg[gid] : 0;
    buf[threadIdx.x] = v;
    __syncthreads();
    for (int off = 1; off < 1024; off <<= 1) {
        const int t = (threadIdx.x >= off) ? buf[threadIdx.x - off] : 0;
        __syncthreads();
        buf[threadIdx.x] += t;
        __syncthreads();
    }
    if (gid < n) incl[gid] = buf[threadIdx.x];
    if (threadIdx.x == 1023) btot[blockIdx.x] = buf[1023];
}

__global__ void scan2_kernel(int* __restrict__ btot, int nb)
{
    if (threadIdx.x == 0 && blockIdx.x == 0) {
        int run = 0;
        for (int i = 0; i < nb; ++i) { const int t = btot[i]; btot[i] = run; run += t; }
    }
}

__global__ void scan3_kernel(const int* __restrict__ incl, const int* __restrict__ deg,
                             const int* __restrict__ btot, int* __restrict__ offs, int n)
{
    const int gid = blockIdx.x * 256 + threadIdx.x;
    if (gid < n) offs[gid] = incl[gid] - deg[gid] + btot[gid >> 10];
}

__global__ void fill_kernel(const int* __restrict__ src, const int* __restrict__ dst,
                            const int* __restrict__ offs, int* __restrict__ cursor,
                            int* __restrict__ csr, int E)
{
    const int e = blockIdx.x * 256 + threadIdx.x;
    if (e < E) {
        const int s = src[e];
        const int pos = atomicAdd(&cursor[s], 1);
        csr[offs[s] + pos] = dst[e];
    }
}

__global__ __launch_bounds__(256) void aggregate_kernel(
    const unsigned short* __restrict__ hb, const int* __restrict__ offs,
    const int* __restrict__ csr, unsigned short* __restrict__ outp, int n, int E)
{
    const int node = blockIdx.x * 4 + (threadIdx.x >> 6);
    const int lane = threadIdx.x & 63;
    if (node >= n) return;
    const int e4 = lane >> 4;
    const int p  = lane & 15;
    const int s = offs[node];
    const int e = (node == n - 1) ? E : offs[node + 1];
    float a[8] = {};
    for (int i = s + e4; i < e; i += 4) {
        const int d = csr[i];
        const uint4 u = *(const uint4*)(hb + (size_t)d * 128 + p * 8);
        a[0] += blo(u.x); a[1] += bhi(u.x);
        a[2] += blo(u.y); a[3] += bhi(u.y);
        a[4] += blo(u.z); a[5] += bhi(u.z);
        a[6] += blo(u.w); a[7] += bhi(u.w);
    }
    #pragma unroll
    for (int i = 0; i < 8; ++i) {
        a[i] += __shfl_xor(a[i], 16);
        a[i] += __shfl_xor(a[i], 32);
    }
    if (e4 == 0) {
        uint4 ow;
        ow.x = pk(a[0], a[1]); ow.y = pk(a[2], a[3]);
        ow.z = pk(a[4], a[5]); ow.w = pk(a[6], a[7]);
        *(uint4*)(outp + (size_t)node * 128 + p * 8) = ow;
    }
}

// ---------------------------------------------------------------------------
extern "C" void kernel_launch(void* const* d_in, const int* in_sizes, int n_in,
                              void* d_out, int out_size, void* d_ws, size_t ws_size,
                              hipStream_t stream)
{
    const float* x        = (const float*)d_in[0];
    const int*   samples  = (const int*)d_in[1];
    const int*   esrc     = (const int*)d_in[2];
    const int*   edst     = (const int*)d_in[3];
    const float* t_in_w   = (const float*)d_in[4];   // [3][384][128]
    const float* t_in_b   = (const float*)d_in[5];
    const float* t_out_w  = (const float*)d_in[6];   // [3][128][128]
    const float* t_out_b  = (const float*)d_in[7];
    const float* t_ffn_w1 = (const float*)d_in[8];   // [3][512][128]
    const float* t_ffn_b1 = (const float*)d_in[9];
    const float* t_ffn_w2 = (const float*)d_in[10];  // [3][128][512]
    const float* t_ffn_b2 = (const float*)d_in[11];
    const float* t_ln1_g  = (const float*)d_in[12];
    const float* t_ln1_b  = (const float*)d_in[13];
    const float* t_ln2_g  = (const float*)d_in[14];
    const float* t_ln2_b  = (const float*)d_in[15];
    const float* g_w      = (const float*)d_in[16];  // [2][128][256]
    const float* g_b      = (const float*)d_in[17];
    const float* g_ln_g   = (const float*)d_in[18];
    const float* g_ln_b   = (const float*)d_in[19];

    const int N = in_sizes[0] / DM;
    const int E = in_sizes[2];

    float* h = (float*)d_out;                        // [N][128] fp32 hidden

    // ---- workspace layout ----
    unsigned short* wbuf = (unsigned short*)d_ws;    // bf16 weights
    unsigned short* w_in  = wbuf;                    // 3*384*128 = 147456
    unsigned short* w_out = w_in  + 147456;          // 3*128*128 = 49152
    unsigned short* w_f1  = w_out + 49152;           // 3*512*128 = 196608
    unsigned short* w_f2  = w_f1  + 196608;          // 3*128*512 = 196608
    unsigned short* w_g   = w_f2  + 196608;          // 2*128*256 = 65536
    unsigned short* hb    = w_g   + 65536;           // [N][128] bf16 hidden
    unsigned short* Abf   = hb  + (size_t)N * 128;   // [N][512] QKV / FFN hidden
    unsigned short* Bbf   = Abf + (size_t)N * 512;   // [N][128] ctx / neigh
    int* offs   = (int*)(Bbf + (size_t)N * 128);
    int* cursor = offs + N;
    int* csr    = cursor + N;
    int* incl   = csr + E;
    int* btot   = incl + N;                          // + ~64

    const int mt = (N + 63) / 64;
    const dim3 blk(256);

    // h = x (fp32) ; hb = bf16(x)
    hipMemcpyAsync(h, x, (size_t)N * DM * sizeof(float), hipMemcpyDeviceToDevice, stream);
    cvt_kernel<<<((N * DM) / 4 + 255) / 256, blk, 0, stream>>>(x, hb, N * DM);

    // ---- convert weights to bf16 (once per call) ----
    cvt_kernel<<<(147456 / 4 + 255) / 256, blk, 0, stream>>>(t_in_w,   w_in,  147456);
    cvt_kernel<<<(49152  / 4 + 255) / 256, blk, 0, stream>>>(t_out_w,  w_out, 49152);
    cvt_kernel<<<(196608 / 4 + 255) / 256, blk, 0, stream>>>(t_ffn_w1, w_f1,  196608);
    cvt_kernel<<<(196608 / 4 + 255) / 256, blk, 0, stream>>>(t_ffn_w2, w_f2,  196608);
    cvt_kernel<<<(65536  / 4 + 255) / 256, blk, 0, stream>>>(g_w,      w_g,   65536);

    // ---- build CSR once ----
    const int nb = (N + 1023) / 1024;
    hipMemsetAsync(cursor, 0, N * sizeof(int), stream);
    count_kernel<<<(E + 255) / 256, blk, 0, stream>>>(esrc, cursor, E);
    scan1_kernel<<<nb, 1024, 0, stream>>>(cursor, incl, btot, N);
    scan2_kernel<<<1, 64, 0, stream>>>(btot, nb);
    scan3_kernel<<<(N + 255) / 256, blk, 0, stream>>>(incl, cursor, btot, offs, N);
    hipMemsetAsync(cursor, 0, N * sizeof(int), stream);
    fill_kernel<<<(E + 255) / 256, blk, 0, stream>>>(esrc, edst, offs, cursor, csr, E);

    const int pn_grid = (N + 3) / 4;     // wave-per-node kernels

    for (int layer = 0; layer < 5; ++layer) {
        if (layer == 1 || layer == 3) {
            // ---------------- GNN block ----------------
            const int i = (layer == 1) ? 0 : 1;
            aggregate_kernel<<<pn_grid, blk, 0, stream>>>(hb, offs, csr, Bbf, N, E);
            gemm_ln<256, true, 128><<<mt, blk, 0, stream>>>(
                hb, Bbf, w_g + (size_t)i * 32768, g_b + i * 128, h,
                g_ln_g + i * 128, g_ln_b + i * 128, h, hb, N);
        } else {
            // ---------------- Transformer block ----------------
            const int i = (layer == 0) ? 0 : (layer == 2 ? 1 : 2);
            // QKV = h @ in_w^T + in_b (project THEN gather) -> bf16
            gemm_mfma<128, 384, false><<<dim3(mt, 6), blk, 0, stream>>>(
                hb, w_in + (size_t)i * 49152, t_in_b + i * 384, Abf, N);
            attn_kernel<<<pn_grid, blk, 0, stream>>>(Abf, samples, Bbf, N);
            gemm_ln<128, false, 0><<<mt, blk, 0, stream>>>(
                Bbf, nullptr, w_out + (size_t)i * 16384, t_out_b + i * 128, h,
                t_ln1_g + i * 128, t_ln1_b + i * 128, h, hb, N);
            gemm_mfma<128, 512, true><<<dim3(mt, 8), blk, 0, stream>>>(
                hb, w_f1 + (size_t)i * 65536, t_ffn_b1 + i * 512, Abf, N);
            gemm_ln<512, false, 0><<<mt, blk, 0, stream>>>(
                Abf, nullptr, w_f2 + (size_t)i * 65536, t_ffn_b2 + i * 128, h,
                t_ln2_g + i * 128, t_ln2_b + i * 128, h, hb, N);
        }
    }
}

// Round 4
// 1250.838 us; speedup vs baseline: 1.9392x; 1.0719x over previous
//
#include <hip/hip_runtime.h>

#define DM 128          // model dim
#define KS 20           // attention samples
#define BW 512          // CSR bucket width (nodes)
#define BSH 9           // log2(BW)
#define MAXB 128        // max buckets (N <= 65536)

typedef __attribute__((ext_vector_type(8))) short short8;   // 8 bf16 (4 VGPRs)
typedef __attribute__((ext_vector_type(4))) float f32x4;

__device__ __forceinline__ unsigned short f2b(float f) {
    unsigned u = __float_as_uint(f);
    u += 0x7fff + ((u >> 16) & 1);          // RNE
    return (unsigned short)(u >> 16);
}
__device__ __forceinline__ float blo(unsigned u) { return __uint_as_float(u << 16); }
__device__ __forceinline__ float bhi(unsigned u) { return __uint_as_float(u & 0xffff0000u); }
__device__ __forceinline__ unsigned pk(float a, float b) {
    return (unsigned)f2b(a) | ((unsigned)f2b(b) << 16);
}

// ---------------------------------------------------------------------------
// x -> h (fp32 copy) + hb (bf16), float4 wide
// ---------------------------------------------------------------------------
__global__ __launch_bounds__(256) void xcvt_kernel(
    const float* __restrict__ x, float* __restrict__ h,
    unsigned short* __restrict__ hb, int n)
{
    const int i = (blockIdx.x * 256 + threadIdx.x) * 4;
    if (i < n) {
        const float4 v = *(const float4*)(x + i);
        *(float4*)(h + i) = v;
        ((unsigned*)hb)[i / 2]     = pk(v.x, v.y);
        ((unsigned*)hb)[i / 2 + 1] = pk(v.z, v.w);
    }
}

// ---------------------------------------------------------------------------
// All weight tensors -> one contiguous bf16 buffer (segment offsets are
// compile-time; wbuf layout matches the pointer arithmetic in kernel_launch).
// ---------------------------------------------------------------------------
__global__ __launch_bounds__(256) void wcvt_kernel(
    const float* __restrict__ t_in_w,  const float* __restrict__ t_out_w,
    const float* __restrict__ t_ffn_w1, const float* __restrict__ t_ffn_w2,
    const float* __restrict__ g_w, unsigned short* __restrict__ wbuf)
{
    const int i4 = (blockIdx.x * 256 + threadIdx.x) * 4;
    if (i4 >= 655360) return;
    const float* src; int rel;
    if      (i4 < 147456) { src = t_in_w;   rel = i4; }
    else if (i4 < 196608) { src = t_out_w;  rel = i4 - 147456; }
    else if (i4 < 393216) { src = t_ffn_w1; rel = i4 - 196608; }
    else if (i4 < 589824) { src = t_ffn_w2; rel = i4 - 393216; }
    else                  { src = g_w;      rel = i4 - 589824; }
    const float4 v = *(const float4*)(src + rel);
    ((unsigned*)wbuf)[i4 / 2]     = pk(v.x, v.y);
    ((unsigned*)wbuf)[i4 / 2 + 1] = pk(v.z, v.w);
}

// ---------------------------------------------------------------------------
// Plain MFMA GEMM (bf16 out): out = X@W^T + bias, opt ReLU. Block 64x64.
// A-frag: m=lane&15, k=quad*8+j ; C/D: col=lane&15, row=quad*4+reg. (verified R2)
// ---------------------------------------------------------------------------
template <int CI, int CO, bool RELU>
__global__ __launch_bounds__(256) void gemm_mfma(
    const unsigned short* __restrict__ X,
    const unsigned short* __restrict__ W, const float* __restrict__ bias,
    unsigned short* __restrict__ outB, int M)
{
    const int tid  = threadIdx.x;
    const int wave = tid >> 6;
    const int lane = tid & 63;
    const int m0 = blockIdx.x * 64 + (wave >> 1) * 32;
    const int c0 = blockIdx.y * 64 + (wave & 1) * 32;
    const int lrow = lane & 15;
    const int quad = lane >> 4;

    f32x4 acc[2][2];
    #pragma unroll
    for (int i = 0; i < 2; ++i)
        #pragma unroll
        for (int j = 0; j < 2; ++j)
            acc[i][j] = (f32x4){0.f, 0.f, 0.f, 0.f};

    const int r0 = m0 + lrow;
    const int r1 = m0 + 16 + lrow;
    const bool v0 = r0 < M, v1 = r1 < M;

    #pragma unroll
    for (int k0 = 0; k0 < CI; k0 += 32) {
        const int ko = k0 + quad * 8;
        short8 a0 = {}, a1 = {};
        if (v0) a0 = *(const short8*)(X + (size_t)r0 * CI + ko);
        if (v1) a1 = *(const short8*)(X + (size_t)r1 * CI + ko);
        const short8 b0 = *(const short8*)(W + (size_t)(c0 + lrow) * CI + ko);
        const short8 b1 = *(const short8*)(W + (size_t)(c0 + 16 + lrow) * CI + ko);
        acc[0][0] = __builtin_amdgcn_mfma_f32_16x16x32_bf16(a0, b0, acc[0][0], 0, 0, 0);
        acc[0][1] = __builtin_amdgcn_mfma_f32_16x16x32_bf16(a0, b1, acc[0][1], 0, 0, 0);
        acc[1][0] = __builtin_amdgcn_mfma_f32_16x16x32_bf16(a1, b0, acc[1][0], 0, 0, 0);
        acc[1][1] = __builtin_amdgcn_mfma_f32_16x16x32_bf16(a1, b1, acc[1][1], 0, 0, 0);
    }

    #pragma unroll
    for (int i = 0; i < 2; ++i) {
        const int rb = m0 + i * 16 + quad * 4;
        #pragma unroll
        for (int j = 0; j < 2; ++j) {
            const int col = c0 + j * 16 + lrow;
            const float bsv = bias[col];
            #pragma unroll
            for (int r = 0; r < 4; ++r) {
                const int row = rb + r;
                if (row < M) {
                    float v = acc[i][j][r] + bsv;
                    if (RELU) v = fmaxf(v, 0.f);
                    outB[(size_t)row * CO + col] = f2b(v);
                }
            }
        }
    }
}

// ---------------------------------------------------------------------------
// Fused GEMM(CO=128) + residual + LayerNorm. (verified R3)
// ---------------------------------------------------------------------------
template <int CI, bool RELU, int SPLIT>
__global__ __launch_bounds__(256) void gemm_ln(
    const unsigned short* __restrict__ X0, const unsigned short* __restrict__ X1,
    const unsigned short* __restrict__ W, const float* __restrict__ bias,
    const float* __restrict__ resid,
    const float* __restrict__ g, const float* __restrict__ be,
    float* __restrict__ hF, unsigned short* __restrict__ hB, int M)
{
    __shared__ float psum[64][2][2];   // [row][wave-col][{sum,sumsq}]
    __shared__ float stats[64][2];     // [row][{mean,rstd}]

    const int tid  = threadIdx.x;
    const int wave = tid >> 6;
    const int lane = tid & 63;
    const int wr = (wave >> 1) * 32;
    const int wc = wave & 1;
    const int m0 = blockIdx.x * 64 + wr;
    const int c0 = wc * 64;
    const int lrow = lane & 15;
    const int quad = lane >> 4;

    f32x4 acc[2][4];
    #pragma unroll
    for (int i = 0; i < 2; ++i)
        #pragma unroll
        for (int j = 0; j < 4; ++j)
            acc[i][j] = (f32x4){0.f, 0.f, 0.f, 0.f};

    const int r0 = m0 + lrow;
    const int r1 = m0 + 16 + lrow;
    const bool v0 = r0 < M, v1 = r1 < M;

    for (int k0 = 0; k0 < CI; k0 += 32) {
        const unsigned short* xs;
        int kk, stride;
        if (SPLIT > 0 && k0 >= SPLIT) { xs = X1; kk = k0 - SPLIT; stride = CI - SPLIT; }
        else                          { xs = X0; kk = k0;         stride = (SPLIT > 0) ? SPLIT : CI; }
        const int ko = kk + quad * 8;
        short8 a0 = {}, a1 = {};
        if (v0) a0 = *(const short8*)(xs + (size_t)r0 * stride + ko);
        if (v1) a1 = *(const short8*)(xs + (size_t)r1 * stride + ko);
        const int kw = k0 + quad * 8;
        #pragma unroll
        for (int j = 0; j < 4; ++j) {
            const short8 bf = *(const short8*)(W + (size_t)(c0 + j * 16 + lrow) * CI + kw);
            acc[0][j] = __builtin_amdgcn_mfma_f32_16x16x32_bf16(a0, bf, acc[0][j], 0, 0, 0);
            acc[1][j] = __builtin_amdgcn_mfma_f32_16x16x32_bf16(a1, bf, acc[1][j], 0, 0, 0);
        }
    }

    float bcol[4], gcol[4], bec[4];
    #pragma unroll
    for (int j = 0; j < 4; ++j) {
        const int col = c0 + j * 16 + lrow;
        bcol[j] = bias[col];
        gcol[j] = g[col];
        bec[j]  = be[col];
    }

    float vals[2][4][4];
    #pragma unroll
    for (int i = 0; i < 2; ++i) {
        #pragma unroll
        for (int r = 0; r < 4; ++r) {
            const int lrel = wr + i * 16 + quad * 4 + r;
            const int row = blockIdx.x * 64 + lrel;
            const bool vr = row < M;
            float s = 0.f, s2 = 0.f;
            #pragma unroll
            for (int j = 0; j < 4; ++j) {
                const int col = c0 + j * 16 + lrow;
                float v = acc[i][j][r] + bcol[j];
                if (RELU) v = fmaxf(v, 0.f);
                if (vr) v += resid[(size_t)row * 128 + col];
                vals[i][j][r] = v;
                s += v; s2 += v * v;
            }
            s  += __shfl_xor(s, 1);  s  += __shfl_xor(s, 2);
            s  += __shfl_xor(s, 4);  s  += __shfl_xor(s, 8);
            s2 += __shfl_xor(s2, 1); s2 += __shfl_xor(s2, 2);
            s2 += __shfl_xor(s2, 4); s2 += __shfl_xor(s2, 8);
            if (lrow == 0) { psum[lrel][wc][0] = s; psum[lrel][wc][1] = s2; }
        }
    }
    __syncthreads();
    if (tid < 64) {
        const float sum   = psum[tid][0][0] + psum[tid][1][0];
        const float sumsq = psum[tid][0][1] + psum[tid][1][1];
        const float mean = sum * (1.f / 128.f);
        const float var  = sumsq * (1.f / 128.f) - mean * mean;
        stats[tid][0] = mean;
        stats[tid][1] = rsqrtf(var + 1e-5f);
    }
    __syncthreads();

    #pragma unroll
    for (int i = 0; i < 2; ++i) {
        #pragma unroll
        for (int r = 0; r < 4; ++r) {
            const int lrel = wr + i * 16 + quad * 4 + r;
            const int row = blockIdx.x * 64 + lrel;
            if (row < M) {
                const float mean = stats[lrel][0];
                const float rstd = stats[lrel][1];
                #pragma unroll
                for (int j = 0; j < 4; ++j) {
                    const int col = c0 + j * 16 + lrow;
                    const float o = (vals[i][j][r] - mean) * rstd * gcol[j] + bec[j];
                    hF[(size_t)row * 128 + col] = o;
                    hB[(size_t)row * 128 + col] = f2b(o);
                }
            }
        }
    }
}

// ---------------------------------------------------------------------------
// Fused sampled attention, wave per node, FLAT softmax (all 10 K/V loads in
// flight before any reduction). lane = s4*16 + p ; s4 = sample slot, p = dims.
// ---------------------------------------------------------------------------
__global__ __launch_bounds__(256) void attn_kernel(
    const unsigned short* __restrict__ qkv, const int* __restrict__ samples,
    unsigned short* __restrict__ ctx, int n)
{
    const int node = blockIdx.x * 4 + (threadIdx.x >> 6);
    const int lane = threadIdx.x & 63;
    if (node >= n) return;
    const int s4 = lane >> 4;
    const int p  = lane & 15;
    const float scale = 0.17677669529663687f;  // 1/sqrt(32)

    const uint4 qu = *(const uint4*)(qkv + (size_t)node * 384 + p * 8);
    float q[8];
    q[0] = blo(qu.x); q[1] = bhi(qu.x); q[2] = blo(qu.y); q[3] = bhi(qu.y);
    q[4] = blo(qu.z); q[5] = bhi(qu.z); q[6] = blo(qu.w); q[7] = bhi(qu.w);

    int rows[5];
    #pragma unroll
    for (int jj = 0; jj < 5; ++jj)
        rows[jj] = samples[node * KS + jj * 4 + s4];

    uint4 kus[5], vus[5];
    #pragma unroll
    for (int jj = 0; jj < 5; ++jj) {
        const size_t base = (size_t)rows[jj] * 384 + p * 8;
        kus[jj] = *(const uint4*)(qkv + base + 128);
        vus[jj] = *(const uint4*)(qkv + base + 256);
    }

    float sc[5];
    #pragma unroll
    for (int jj = 0; jj < 5; ++jj) {
        const uint4 ku = kus[jj];
        float d = q[0] * blo(ku.x) + q[1] * bhi(ku.x)
                + q[2] * blo(ku.y) + q[3] * bhi(ku.y)
                + q[4] * blo(ku.z) + q[5] * bhi(ku.z)
                + q[6] * blo(ku.w) + q[7] * bhi(ku.w);
        d += __shfl_xor(d, 1);
        d += __shfl_xor(d, 2);              // head-group (4 lanes) total
        sc[jj] = d * scale;
    }

    float m = sc[0];
    #pragma unroll
    for (int jj = 1; jj < 5; ++jj) m = fmaxf(m, sc[jj]);
    m = fmaxf(m, __shfl_xor(m, 16));
    m = fmaxf(m, __shfl_xor(m, 32));        // global max over 20 samples

    float l = 0.f;
    float o[8] = {};
    #pragma unroll
    for (int jj = 0; jj < 5; ++jj) {
        const float e = __expf(sc[jj] - m);
        l += e;
        const uint4 vu = vus[jj];
        o[0] += e * blo(vu.x); o[1] += e * bhi(vu.x);
        o[2] += e * blo(vu.y); o[3] += e * bhi(vu.y);
        o[4] += e * blo(vu.z); o[5] += e * bhi(vu.z);
        o[6] += e * blo(vu.w); o[7] += e * bhi(vu.w);
    }

    l += __shfl_xor(l, 16); l += __shfl_xor(l, 32);
    #pragma unroll
    for (int i = 0; i < 8; ++i) {
        o[i] += __shfl_xor(o[i], 16);
        o[i] += __shfl_xor(o[i], 32);
    }
    if (s4 == 0) {
        const float inv = 1.f / l;
        uint4 ow;
        ow.x = pk(o[0] * inv, o[1] * inv);
        ow.y = pk(o[2] * inv, o[3] * inv);
        ow.z = pk(o[4] * inv, o[5] * inv);
        ow.w = pk(o[6] * inv, o[7] * inv);
        *(uint4*)(ctx + (size_t)node * 128 + p * 8) = ow;
    }
}

// ---------------------------------------------------------------------------
// Bucketed CSR build.
// A1: per-block LDS histogram of src buckets -> global bucket counts.
// ---------------------------------------------------------------------------
__global__ __launch_bounds__(256) void bcount_kernel(
    const int* __restrict__ esrc, int* __restrict__ bcnt, int E)
{
    __shared__ int hist[MAXB];
    for (int i = threadIdx.x; i < MAXB; i += 256) hist[i] = 0;
    __syncthreads();
    const int stride = gridDim.x * 256;
    for (int e = blockIdx.x * 256 + threadIdx.x; e < E; e += stride)
        atomicAdd(&hist[esrc[e] >> BSH], 1);
    __syncthreads();
    for (int i = threadIdx.x; i < MAXB; i += 256)
        if (hist[i]) atomicAdd(&bcnt[i], hist[i]);
}

// A2: tiny serial scan over <=128 buckets (also inits write cursors)
__global__ void bscan_kernel(const int* __restrict__ bcnt, int* __restrict__ boffs,
                             int* __restrict__ bcur, int NB)
{
    if (threadIdx.x == 0 && blockIdx.x == 0) {
        int run = 0;
        for (int i = 0; i < NB; ++i) { boffs[i] = run; bcur[i] = run; run += bcnt[i]; }
        boffs[NB] = run;
    }
}

// A3: LDS counting-sort of 2048-edge chunks by bucket; per-bucket run reserved
// with ONE global atomic; runs written out contiguously (dense writebacks).
__global__ __launch_bounds__(256) void bscatter_kernel(
    const int* __restrict__ esrc, const int* __restrict__ edst,
    int* __restrict__ bcur, uint2* __restrict__ ebuck, int E)
{
    __shared__ int hist[MAXB], scanb[MAXB], lstart[MAXB], gbase[MAXB], cnt2[MAXB];
    __shared__ uint2 stage[2048];
    __shared__ int gaddr[2048];
    const int t = threadIdx.x;
    const int base = blockIdx.x * 2048;
    const int nchunk = min(2048, E - base);
    for (int i = t; i < MAXB; i += 256) { hist[i] = 0; cnt2[i] = 0; }
    __syncthreads();

    int es[8], ed[8], eb[8];
    #pragma unroll
    for (int i = 0; i < 8; ++i) {
        const int idx = base + i * 256 + t;
        if (idx < E) {
            es[i] = esrc[idx]; ed[i] = edst[idx];
            eb[i] = es[i] >> BSH;
            atomicAdd(&hist[eb[i]], 1);
        } else eb[i] = -1;
    }
    __syncthreads();

    if (t < MAXB) scanb[t] = hist[t];
    __syncthreads();
    for (int off = 1; off < MAXB; off <<= 1) {
        int v = 0;
        if (t < MAXB && t >= off) v = scanb[t - off];
        __syncthreads();
        if (t < MAXB) scanb[t] += v;
        __syncthreads();
    }
    if (t < MAXB) {
        lstart[t] = scanb[t] - hist[t];
        if (hist[t] > 0) gbase[t] = atomicAdd(&bcur[t], hist[t]);
    }
    __syncthreads();

    #pragma unroll
    for (int i = 0; i < 8; ++i) {
        if (eb[i] >= 0) {
            const int li = atomicAdd(&cnt2[eb[i]], 1);
            const int pos = lstart[eb[i]] + li;
            stage[pos] = make_uint2((unsigned)es[i], (unsigned)ed[i]);
            gaddr[pos] = gbase[eb[i]] + li;
        }
    }
    __syncthreads();
    for (int i = t; i < nchunk; i += 256)
        ebuck[gaddr[i]] = stage[i];
}

// B: one block per bucket: LDS deg hist -> LDS scan -> offs (global, dense)
//    -> LDS-cursor scatter into this bucket's private csr region.
__global__ __launch_bounds__(256) void bbuild_kernel(
    const uint2* __restrict__ ebuck, const int* __restrict__ bcnt,
    const int* __restrict__ boffs, int* __restrict__ offs, int* __restrict__ csr, int N)
{
    __shared__ int degl[BW], sbuf[BW], curl[BW];
    const int b = blockIdx.x;
    const int t = threadIdx.x;
    const int nbase = b * BW;
    const int nn = min(BW, N - nbase);
    const int estart = boffs[b];
    const int ecnt = bcnt[b];

    for (int i = t; i < BW; i += 256) { degl[i] = 0; curl[i] = 0; }
    __syncthreads();
    for (int i = t; i < ecnt; i += 256)
        atomicAdd(&degl[(int)ebuck[estart + i].x - nbase], 1);
    __syncthreads();

    sbuf[t] = degl[t]; sbuf[t + 256] = degl[t + 256];
    __syncthreads();
    for (int off = 1; off < BW; off <<= 1) {
        const int i1 = t + 256;
        int v0 = (t  >= off) ? sbuf[t  - off] : 0;
        int v1 = (i1 >= off) ? sbuf[i1 - off] : 0;
        __syncthreads();
        sbuf[t] += v0; sbuf[i1] += v1;
        __syncthreads();
    }
    {   // exclusive in-place (own entries only) + dense global offs write
        const int e0 = sbuf[t] - degl[t];
        const int e1 = sbuf[t + 256] - degl[t + 256];
        sbuf[t] = e0; sbuf[t + 256] = e1;
        if (t < nn)       offs[nbase + t]       = estart + e0;
        if (t + 256 < nn) offs[nbase + t + 256] = estart + e1;
    }
    __syncthreads();
    for (int i = t; i < ecnt; i += 256) {
        const uint2 pr = ebuck[estart + i];
        const int s = (int)pr.x - nbase;
        const int pos = estart + sbuf[s] + atomicAdd(&curl[s], 1);
        csr[pos] = (int)pr.y;
    }
}

// ---------------------------------------------------------------------------
// Aggregation: wave/node, 4 edge slots x 2-deep unroll (8 loads in flight)
// ---------------------------------------------------------------------------
__global__ __launch_bounds__(256) void aggregate_kernel(
    const unsigned short* __restrict__ hb, const int* __restrict__ offs,
    const int* __restrict__ csr, unsigned short* __restrict__ outp, int n, int E)
{
    const int node = blockIdx.x * 4 + (threadIdx.x >> 6);
    const int lane = threadIdx.x & 63;
    if (node >= n) return;
    const int e4 = lane >> 4;
    const int p  = lane & 15;
    const int s = offs[node];
    const int e = (node == n - 1) ? E : offs[node + 1];
    float a[8] = {};
    int i = s + e4;
    for (; i + 4 < e; i += 8) {
        const int d0 = csr[i], d1 = csr[i + 4];
        const uint4 u0 = *(const uint4*)(hb + (size_t)d0 * 128 + p * 8);
        const uint4 u1 = *(const uint4*)(hb + (size_t)d1 * 128 + p * 8);
        a[0] += blo(u0.x) + blo(u1.x); a[1] += bhi(u0.x) + bhi(u1.x);
        a[2] += blo(u0.y) + blo(u1.y); a[3] += bhi(u0.y) + bhi(u1.y);
        a[4] += blo(u0.z) + blo(u1.z); a[5] += bhi(u0.z) + bhi(u1.z);
        a[6] += blo(u0.w) + blo(u1.w); a[7] += bhi(u0.w) + bhi(u1.w);
    }
    for (; i < e; i += 4) {
        const uint4 u = *(const uint4*)(hb + (size_t)csr[i] * 128 + p * 8);
        a[0] += blo(u.x); a[1] += bhi(u.x);
        a[2] += blo(u.y); a[3] += bhi(u.y);
        a[4] += blo(u.z); a[5] += bhi(u.z);
        a[6] += blo(u.w); a[7] += bhi(u.w);
    }
    #pragma unroll
    for (int k = 0; k < 8; ++k) {
        a[k] += __shfl_xor(a[k], 16);
        a[k] += __shfl_xor(a[k], 32);
    }
    if (e4 == 0) {
        uint4 ow;
        ow.x = pk(a[0], a[1]); ow.y = pk(a[2], a[3]);
        ow.z = pk(a[4], a[5]); ow.w = pk(a[6], a[7]);
        *(uint4*)(outp + (size_t)node * 128 + p * 8) = ow;
    }
}

// ---------------------------------------------------------------------------
extern "C" void kernel_launch(void* const* d_in, const int* in_sizes, int n_in,
                              void* d_out, int out_size, void* d_ws, size_t ws_size,
                              hipStream_t stream)
{
    const float* x        = (const float*)d_in[0];
    const int*   samples  = (const int*)d_in[1];
    const int*   esrc     = (const int*)d_in[2];
    const int*   edst     = (const int*)d_in[3];
    const float* t_in_w   = (const float*)d_in[4];   // [3][384][128]
    const float* t_in_b   = (const float*)d_in[5];
    const float* t_out_w  = (const float*)d_in[6];   // [3][128][128]
    const float* t_out_b  = (const float*)d_in[7];
    const float* t_ffn_w1 = (const float*)d_in[8];   // [3][512][128]
    const float* t_ffn_b1 = (const float*)d_in[9];
    const float* t_ffn_w2 = (const float*)d_in[10];  // [3][128][512]
    const float* t_ffn_b2 = (const float*)d_in[11];
    const float* t_ln1_g  = (const float*)d_in[12];
    const float* t_ln1_b  = (const float*)d_in[13];
    const float* t_ln2_g  = (const float*)d_in[14];
    const float* t_ln2_b  = (const float*)d_in[15];
    const float* g_w      = (const float*)d_in[16];  // [2][128][256]
    const float* g_b      = (const float*)d_in[17];
    const float* g_ln_g   = (const float*)d_in[18];
    const float* g_ln_b   = (const float*)d_in[19];

    const int N = in_sizes[0] / DM;
    const int E = in_sizes[2];
    const int NB = (N + BW - 1) >> BSH;

    float* h = (float*)d_out;                        // [N][128] fp32 hidden

    // ---- workspace layout ----
    unsigned short* wbuf = (unsigned short*)d_ws;    // bf16 weights (wcvt layout)
    unsigned short* w_in  = wbuf;                    // 3*384*128 = 147456
    unsigned short* w_out = w_in  + 147456;          // 3*128*128 = 49152
    unsigned short* w_f1  = w_out + 49152;           // 3*512*128 = 196608
    unsigned short* w_f2  = w_f1  + 196608;          // 3*128*512 = 196608
    unsigned short* w_g   = w_f2  + 196608;          // 2*128*256 = 65536
    unsigned short* hb    = w_g   + 65536;           // [N][128] bf16 hidden
    unsigned short* Abf   = hb  + (size_t)N * 128;   // [N][512] QKV / FFN hidden
    unsigned short* Bbf   = Abf + (size_t)N * 512;   // [N][128] ctx / neigh
    uint2* ebuck = (uint2*)(Bbf + (size_t)N * 128);  // [E] bucketed (src,dst)
    int* offs = (int*)(ebuck + E);                   // [N]
    int* csr  = offs + N;                            // [E]
    int* bcnt  = csr + E;                            // [MAXB]
    int* boffs = bcnt + MAXB;                        // [MAXB+1]
    int* bcur  = boffs + MAXB + 1;                   // [MAXB]

    const int mt = (N + 63) / 64;
    const dim3 blk(256);

    // h = x (fp32) + hb = bf16(x)  [one kernel]
    xcvt_kernel<<<((N * DM) / 4 + 255) / 256, blk, 0, stream>>>(x, h, hb, N * DM);
    // all weights -> bf16 [one kernel]
    wcvt_kernel<<<(655360 / 4 + 255) / 256, blk, 0, stream>>>(
        t_in_w, t_out_w, t_ffn_w1, t_ffn_w2, g_w, wbuf);

    // ---- bucketed CSR build ----
    hipMemsetAsync(bcnt, 0, MAXB * sizeof(int), stream);
    bcount_kernel<<<(E + 2047) / 2048, blk, 0, stream>>>(esrc, bcnt, E);
    bscan_kernel<<<1, 64, 0, stream>>>(bcnt, boffs, bcur, NB);
    bscatter_kernel<<<(E + 2047) / 2048, blk, 0, stream>>>(esrc, edst, bcur, ebuck, E);
    bbuild_kernel<<<NB, blk, 0, stream>>>(ebuck, bcnt, boffs, offs, csr, N);

    const int pn_grid = (N + 3) / 4;     // wave-per-node kernels

    for (int layer = 0; layer < 5; ++layer) {
        if (layer == 1 || layer == 3) {
            // ---------------- GNN block ----------------
            const int i = (layer == 1) ? 0 : 1;
            aggregate_kernel<<<pn_grid, blk, 0, stream>>>(hb, offs, csr, Bbf, N, E);
            gemm_ln<256, true, 128><<<mt, blk, 0, stream>>>(
                hb, Bbf, w_g + (size_t)i * 32768, g_b + i * 128, h,
                g_ln_g + i * 128, g_ln_b + i * 128, h, hb, N);
        } else {
            // ---------------- Transformer block ----------------
            const int i = (layer == 0) ? 0 : (layer == 2 ? 1 : 2);
            // QKV = h @ in_w^T + in_b (project THEN gather) -> bf16
            gemm_mfma<128, 384, false><<<dim3(mt, 6), blk, 0, stream>>>(
                hb, w_in + (size_t)i * 49152, t_in_b + i * 384, Abf, N);
            attn_kernel<<<pn_grid, blk, 0, stream>>>(Abf, samples, Bbf, N);
            gemm_ln<128, false, 0><<<mt, blk, 0, stream>>>(
                Bbf, nullptr, w_out + (size_t)i * 16384, t_out_b + i * 128, h,
                t_ln1_g + i * 128, t_ln1_b + i * 128, h, hb, N);
            gemm_mfma<128, 512, true><<<dim3(mt, 8), blk, 0, stream>>>(
                hb, w_f1 + (size_t)i * 65536, t_ffn_b1 + i * 512, Abf, N);
            gemm_ln<512, false, 0><<<mt, blk, 0, stream>>>(
                Abf, nullptr, w_f2 + (size_t)i * 65536, t_ffn_b2 + i * 128, h,
                t_ln2_g + i * 128, t_ln2_b + i * 128, h, hb, N);
        }
    }
}

// Round 5
// 1101.522 us; speedup vs baseline: 2.2021x; 1.1356x over previous
//
#include <hip/hip_runtime.h>

#define DM 128          // model dim
#define KS 20           // attention samples
#define BW 512          // CSR bucket width (nodes)
#define BSH 9           // log2(BW)
#define MAXB 128        // max buckets (N <= 65536)
#define HP 520          // padded LDS hidden row stride (ffn_fused)

typedef __attribute__((ext_vector_type(8))) short short8;   // 8 bf16 (4 VGPRs)
typedef __attribute__((ext_vector_type(4))) float f32x4;

__device__ __forceinline__ unsigned short f2b(float f) {
    unsigned u = __float_as_uint(f);
    u += 0x7fff + ((u >> 16) & 1);          // RNE
    return (unsigned short)(u >> 16);
}
__device__ __forceinline__ float blo(unsigned u) { return __uint_as_float(u << 16); }
__device__ __forceinline__ float bhi(unsigned u) { return __uint_as_float(u & 0xffff0000u); }
__device__ __forceinline__ unsigned pk(float a, float b) {
    return (unsigned)f2b(a) | ((unsigned)f2b(b) << 16);
}

// ---------------------------------------------------------------------------
// x -> h (fp32 copy) + hb (bf16), float4 wide
// ---------------------------------------------------------------------------
__global__ __launch_bounds__(256) void xcvt_kernel(
    const float* __restrict__ x, float* __restrict__ h,
    unsigned short* __restrict__ hb, int n)
{
    const int i = (blockIdx.x * 256 + threadIdx.x) * 4;
    if (i < n) {
        const float4 v = *(const float4*)(x + i);
        *(float4*)(h + i) = v;
        ((unsigned*)hb)[i / 2]     = pk(v.x, v.y);
        ((unsigned*)hb)[i / 2 + 1] = pk(v.z, v.w);
    }
}

// ---------------------------------------------------------------------------
// All weight tensors -> one contiguous bf16 buffer.
// ---------------------------------------------------------------------------
__global__ __launch_bounds__(256) void wcvt_kernel(
    const float* __restrict__ t_in_w,  const float* __restrict__ t_out_w,
    const float* __restrict__ t_ffn_w1, const float* __restrict__ t_ffn_w2,
    const float* __restrict__ g_w, unsigned short* __restrict__ wbuf)
{
    const int i4 = (blockIdx.x * 256 + threadIdx.x) * 4;
    if (i4 >= 655360) return;
    const float* src; int rel;
    if      (i4 < 147456) { src = t_in_w;   rel = i4; }
    else if (i4 < 196608) { src = t_out_w;  rel = i4 - 147456; }
    else if (i4 < 393216) { src = t_ffn_w1; rel = i4 - 196608; }
    else if (i4 < 589824) { src = t_ffn_w2; rel = i4 - 393216; }
    else                  { src = g_w;      rel = i4 - 589824; }
    const float4 v = *(const float4*)(src + rel);
    ((unsigned*)wbuf)[i4 / 2]     = pk(v.x, v.y);
    ((unsigned*)wbuf)[i4 / 2 + 1] = pk(v.z, v.w);
}

// ---------------------------------------------------------------------------
// MFMA GEMM (bf16 out): out = X@W^T + bias. Block 128x64.
// 4 waves in 2x2: wave = 4 row-tiles x 2 col-tiles (8 MFMA / 6 loads per iter).
// A-frag: m=lane&15, k=quad*8+j ; C/D: col=lane&15, row=quad*4+reg. (verified R2)
// ---------------------------------------------------------------------------
template <int CI, int CO, bool RELU>
__global__ __launch_bounds__(256) void gemm_mfma(
    const unsigned short* __restrict__ X,
    const unsigned short* __restrict__ W, const float* __restrict__ bias,
    unsigned short* __restrict__ outB, int M)
{
    const int tid  = threadIdx.x;
    const int wave = tid >> 6;
    const int lane = tid & 63;
    const int m0 = blockIdx.x * 128 + (wave >> 1) * 64;
    const int c0 = blockIdx.y * 64 + (wave & 1) * 32;
    const int lrow = lane & 15;
    const int quad = lane >> 4;

    f32x4 acc[4][2];
    #pragma unroll
    for (int i = 0; i < 4; ++i)
        #pragma unroll
        for (int j = 0; j < 2; ++j)
            acc[i][j] = (f32x4){0.f, 0.f, 0.f, 0.f};

    int rr[4]; bool vv[4];
    #pragma unroll
    for (int i = 0; i < 4; ++i) { rr[i] = m0 + i * 16 + lrow; vv[i] = rr[i] < M; }

    #pragma unroll
    for (int k0 = 0; k0 < CI; k0 += 32) {
        const int ko = k0 + quad * 8;
        short8 a[4];
        #pragma unroll
        for (int i = 0; i < 4; ++i) {
            a[i] = short8{};
            if (vv[i]) a[i] = *(const short8*)(X + (size_t)rr[i] * CI + ko);
        }
        const short8 b0 = *(const short8*)(W + (size_t)(c0 + lrow) * CI + ko);
        const short8 b1 = *(const short8*)(W + (size_t)(c0 + 16 + lrow) * CI + ko);
        #pragma unroll
        for (int i = 0; i < 4; ++i) {
            acc[i][0] = __builtin_amdgcn_mfma_f32_16x16x32_bf16(a[i], b0, acc[i][0], 0, 0, 0);
            acc[i][1] = __builtin_amdgcn_mfma_f32_16x16x32_bf16(a[i], b1, acc[i][1], 0, 0, 0);
        }
    }

    #pragma unroll
    for (int i = 0; i < 4; ++i) {
        const int rb = m0 + i * 16 + quad * 4;
        #pragma unroll
        for (int j = 0; j < 2; ++j) {
            const int col = c0 + j * 16 + lrow;
            const float bsv = bias[col];
            #pragma unroll
            for (int r = 0; r < 4; ++r) {
                const int row = rb + r;
                if (row < M) {
                    float v = acc[i][j][r] + bsv;
                    if (RELU) v = fmaxf(v, 0.f);
                    outB[(size_t)row * CO + col] = f2b(v);
                }
            }
        }
    }
}

// ---------------------------------------------------------------------------
// Fused GEMM(CO=128) + residual + LayerNorm. (verified R3)
// ---------------------------------------------------------------------------
template <int CI, bool RELU, int SPLIT>
__global__ __launch_bounds__(256) void gemm_ln(
    const unsigned short* __restrict__ X0, const unsigned short* __restrict__ X1,
    const unsigned short* __restrict__ W, const float* __restrict__ bias,
    const float* __restrict__ resid,
    const float* __restrict__ g, const float* __restrict__ be,
    float* __restrict__ hF, unsigned short* __restrict__ hB, int M)
{
    __shared__ float psum[64][2][2];
    __shared__ float stats[64][2];

    const int tid  = threadIdx.x;
    const int wave = tid >> 6;
    const int lane = tid & 63;
    const int wr = (wave >> 1) * 32;
    const int wc = wave & 1;
    const int m0 = blockIdx.x * 64 + wr;
    const int c0 = wc * 64;
    const int lrow = lane & 15;
    const int quad = lane >> 4;

    f32x4 acc[2][4];
    #pragma unroll
    for (int i = 0; i < 2; ++i)
        #pragma unroll
        for (int j = 0; j < 4; ++j)
            acc[i][j] = (f32x4){0.f, 0.f, 0.f, 0.f};

    const int r0 = m0 + lrow;
    const int r1 = m0 + 16 + lrow;
    const bool v0 = r0 < M, v1 = r1 < M;

    for (int k0 = 0; k0 < CI; k0 += 32) {
        const unsigned short* xs;
        int kk, stride;
        if (SPLIT > 0 && k0 >= SPLIT) { xs = X1; kk = k0 - SPLIT; stride = CI - SPLIT; }
        else                          { xs = X0; kk = k0;         stride = (SPLIT > 0) ? SPLIT : CI; }
        const int ko = kk + quad * 8;
        short8 a0 = {}, a1 = {};
        if (v0) a0 = *(const short8*)(xs + (size_t)r0 * stride + ko);
        if (v1) a1 = *(const short8*)(xs + (size_t)r1 * stride + ko);
        const int kw = k0 + quad * 8;
        #pragma unroll
        for (int j = 0; j < 4; ++j) {
            const short8 bf = *(const short8*)(W + (size_t)(c0 + j * 16 + lrow) * CI + kw);
            acc[0][j] = __builtin_amdgcn_mfma_f32_16x16x32_bf16(a0, bf, acc[0][j], 0, 0, 0);
            acc[1][j] = __builtin_amdgcn_mfma_f32_16x16x32_bf16(a1, bf, acc[1][j], 0, 0, 0);
        }
    }

    float bcol[4], gcol[4], bec[4];
    #pragma unroll
    for (int j = 0; j < 4; ++j) {
        const int col = c0 + j * 16 + lrow;
        bcol[j] = bias[col];
        gcol[j] = g[col];
        bec[j]  = be[col];
    }

    float vals[2][4][4];
    #pragma unroll
    for (int i = 0; i < 2; ++i) {
        #pragma unroll
        for (int r = 0; r < 4; ++r) {
            const int lrel = wr + i * 16 + quad * 4 + r;
            const int row = blockIdx.x * 64 + lrel;
            const bool vr = row < M;
            float s = 0.f, s2 = 0.f;
            #pragma unroll
            for (int j = 0; j < 4; ++j) {
                const int col = c0 + j * 16 + lrow;
                float v = acc[i][j][r] + bcol[j];
                if (RELU) v = fmaxf(v, 0.f);
                if (vr) v += resid[(size_t)row * 128 + col];
                vals[i][j][r] = v;
                s += v; s2 += v * v;
            }
            s  += __shfl_xor(s, 1);  s  += __shfl_xor(s, 2);
            s  += __shfl_xor(s, 4);  s  += __shfl_xor(s, 8);
            s2 += __shfl_xor(s2, 1); s2 += __shfl_xor(s2, 2);
            s2 += __shfl_xor(s2, 4); s2 += __shfl_xor(s2, 8);
            if (lrow == 0) { psum[lrel][wc][0] = s; psum[lrel][wc][1] = s2; }
        }
    }
    __syncthreads();
    if (tid < 64) {
        const float sum   = psum[tid][0][0] + psum[tid][1][0];
        const float sumsq = psum[tid][0][1] + psum[tid][1][1];
        const float mean = sum * (1.f / 128.f);
        const float var  = sumsq * (1.f / 128.f) - mean * mean;
        stats[tid][0] = mean;
        stats[tid][1] = rsqrtf(var + 1e-5f);
    }
    __syncthreads();

    #pragma unroll
    for (int i = 0; i < 2; ++i) {
        #pragma unroll
        for (int r = 0; r < 4; ++r) {
            const int lrel = wr + i * 16 + quad * 4 + r;
            const int row = blockIdx.x * 64 + lrel;
            if (row < M) {
                const float mean = stats[lrel][0];
                const float rstd = stats[lrel][1];
                #pragma unroll
                for (int j = 0; j < 4; ++j) {
                    const int col = c0 + j * 16 + lrow;
                    const float o = (vals[i][j][r] - mean) * rstd * gcol[j] + bec[j];
                    hF[(size_t)row * 128 + col] = o;
                    hB[(size_t)row * 128 + col] = f2b(o);
                }
            }
        }
    }
}

// ---------------------------------------------------------------------------
// Fused FFN: out = LN( relu(X@W1^T+b1)@W2^T + b2 + resid ). Block = 64 rows.
// Phase 1: H[64][512] bf16 -> LDS (two 256-col passes, wave owns 64 cols/pass).
// Phase 2: gemm_ln-style 2x2 wave grid, A-frags from LDS, K=512.
// ---------------------------------------------------------------------------
__global__ __launch_bounds__(256) void ffn_fused(
    const unsigned short* __restrict__ X,    // [M][128] bf16
    const unsigned short* __restrict__ W1,   // [512][128]
    const float* __restrict__ b1,
    const unsigned short* __restrict__ W2,   // [128][512]
    const float* __restrict__ b2,
    const float* __restrict__ resid,
    const float* __restrict__ g, const float* __restrict__ be,
    float* __restrict__ hF, unsigned short* __restrict__ hB, int M)
{
    __shared__ unsigned short Hs[64 * HP];   // 66.6 KB
    __shared__ float psum[64][2][2];
    __shared__ float stats[64][2];

    const int tid  = threadIdx.x;
    const int wave = tid >> 6;
    const int lane = tid & 63;
    const int lrow = lane & 15;
    const int quad = lane >> 4;
    const int m0 = blockIdx.x * 64;

    // ---- phase 1: H = relu(X@W1^T + b1) ----
    int rr[4]; bool vv[4];
    #pragma unroll
    for (int i = 0; i < 4; ++i) { rr[i] = m0 + i * 16 + lrow; vv[i] = rr[i] < M; }

    #pragma unroll
    for (int pass = 0; pass < 2; ++pass) {
        const int cb = pass * 256 + wave * 64;
        f32x4 acc[4][4];
        #pragma unroll
        for (int i = 0; i < 4; ++i)
            #pragma unroll
            for (int j = 0; j < 4; ++j)
                acc[i][j] = (f32x4){0.f, 0.f, 0.f, 0.f};

        #pragma unroll
        for (int k0 = 0; k0 < 128; k0 += 32) {
            const int ko = k0 + quad * 8;
            short8 a[4];
            #pragma unroll
            for (int i = 0; i < 4; ++i) {
                a[i] = short8{};
                if (vv[i]) a[i] = *(const short8*)(X + (size_t)rr[i] * 128 + ko);
            }
            #pragma unroll
            for (int j = 0; j < 4; ++j) {
                const short8 bf = *(const short8*)(W1 + (size_t)(cb + j * 16 + lrow) * 128 + ko);
                #pragma unroll
                for (int i = 0; i < 4; ++i)
                    acc[i][j] = __builtin_amdgcn_mfma_f32_16x16x32_bf16(a[i], bf, acc[i][j], 0, 0, 0);
            }
        }
        float bc[4];
        #pragma unroll
        for (int j = 0; j < 4; ++j) bc[j] = b1[cb + j * 16 + lrow];
        #pragma unroll
        for (int i = 0; i < 4; ++i) {
            #pragma unroll
            for (int r = 0; r < 4; ++r) {
                const int lrel = i * 16 + quad * 4 + r;
                #pragma unroll
                for (int j = 0; j < 4; ++j) {
                    const int col = cb + j * 16 + lrow;
                    Hs[lrel * HP + col] = f2b(fmaxf(acc[i][j][r] + bc[j], 0.f));
                }
            }
        }
    }
    __syncthreads();

    // ---- phase 2: Y = H@W2^T + b2 + resid -> LN ----
    const int wr = (wave >> 1) * 32;
    const int wc = wave & 1;
    const int c0 = wc * 64;

    f32x4 acc2[2][4];
    #pragma unroll
    for (int i = 0; i < 2; ++i)
        #pragma unroll
        for (int j = 0; j < 4; ++j)
            acc2[i][j] = (f32x4){0.f, 0.f, 0.f, 0.f};

    #pragma unroll
    for (int k0 = 0; k0 < 512; k0 += 32) {
        const int ko = k0 + quad * 8;
        const short8 a0 = *(const short8*)&Hs[(wr + lrow) * HP + ko];
        const short8 a1 = *(const short8*)&Hs[(wr + 16 + lrow) * HP + ko];
        #pragma unroll
        for (int j = 0; j < 4; ++j) {
            const short8 bf = *(const short8*)(W2 + (size_t)(c0 + j * 16 + lrow) * 512 + ko);
            acc2[0][j] = __builtin_amdgcn_mfma_f32_16x16x32_bf16(a0, bf, acc2[0][j], 0, 0, 0);
            acc2[1][j] = __builtin_amdgcn_mfma_f32_16x16x32_bf16(a1, bf, acc2[1][j], 0, 0, 0);
        }
    }

    float bcol[4], gcol[4], bec[4];
    #pragma unroll
    for (int j = 0; j < 4; ++j) {
        const int col = c0 + j * 16 + lrow;
        bcol[j] = b2[col];
        gcol[j] = g[col];
        bec[j]  = be[col];
    }

    float vals[2][4][4];
    #pragma unroll
    for (int i = 0; i < 2; ++i) {
        #pragma unroll
        for (int r = 0; r < 4; ++r) {
            const int lrel = wr + i * 16 + quad * 4 + r;
            const int row = m0 + lrel;
            const bool vr = row < M;
            float s = 0.f, s2 = 0.f;
            #pragma unroll
            for (int j = 0; j < 4; ++j) {
                const int col = c0 + j * 16 + lrow;
                float v = acc2[i][j][r] + bcol[j];
                if (vr) v += resid[(size_t)row * 128 + col];
                vals[i][j][r] = v;
                s += v; s2 += v * v;
            }
            s  += __shfl_xor(s, 1);  s  += __shfl_xor(s, 2);
            s  += __shfl_xor(s, 4);  s  += __shfl_xor(s, 8);
            s2 += __shfl_xor(s2, 1); s2 += __shfl_xor(s2, 2);
            s2 += __shfl_xor(s2, 4); s2 += __shfl_xor(s2, 8);
            if (lrow == 0) { psum[lrel][wc][0] = s; psum[lrel][wc][1] = s2; }
        }
    }
    __syncthreads();
    if (tid < 64) {
        const float sum   = psum[tid][0][0] + psum[tid][1][0];
        const float sumsq = psum[tid][0][1] + psum[tid][1][1];
        const float mean = sum * (1.f / 128.f);
        const float var  = sumsq * (1.f / 128.f) - mean * mean;
        stats[tid][0] = mean;
        stats[tid][1] = rsqrtf(var + 1e-5f);
    }
    __syncthreads();

    #pragma unroll
    for (int i = 0; i < 2; ++i) {
        #pragma unroll
        for (int r = 0; r < 4; ++r) {
            const int lrel = wr + i * 16 + quad * 4 + r;
            const int row = m0 + lrel;
            if (row < M) {
                const float mean = stats[lrel][0];
                const float rstd = stats[lrel][1];
                #pragma unroll
                for (int j = 0; j < 4; ++j) {
                    const int col = c0 + j * 16 + lrow;
                    const float o = (vals[i][j][r] - mean) * rstd * gcol[j] + bec[j];
                    hF[(size_t)row * 128 + col] = o;
                    hB[(size_t)row * 128 + col] = f2b(o);
                }
            }
        }
    }
}

// ---------------------------------------------------------------------------
// Fused sampled attention, wave per node, flat softmax. (verified R4)
// ---------------------------------------------------------------------------
__global__ __launch_bounds__(256) void attn_kernel(
    const unsigned short* __restrict__ qkv, const int* __restrict__ samples,
    unsigned short* __restrict__ ctx, int n)
{
    const int node = blockIdx.x * 4 + (threadIdx.x >> 6);
    const int lane = threadIdx.x & 63;
    if (node >= n) return;
    const int s4 = lane >> 4;
    const int p  = lane & 15;
    const float scale = 0.17677669529663687f;  // 1/sqrt(32)

    const uint4 qu = *(const uint4*)(qkv + (size_t)node * 384 + p * 8);
    float q[8];
    q[0] = blo(qu.x); q[1] = bhi(qu.x); q[2] = blo(qu.y); q[3] = bhi(qu.y);
    q[4] = blo(qu.z); q[5] = bhi(qu.z); q[6] = blo(qu.w); q[7] = bhi(qu.w);

    int rows[5];
    #pragma unroll
    for (int jj = 0; jj < 5; ++jj)
        rows[jj] = samples[node * KS + jj * 4 + s4];

    uint4 kus[5], vus[5];
    #pragma unroll
    for (int jj = 0; jj < 5; ++jj) {
        const size_t base = (size_t)rows[jj] * 384 + p * 8;
        kus[jj] = *(const uint4*)(qkv + base + 128);
        vus[jj] = *(const uint4*)(qkv + base + 256);
    }

    float sc[5];
    #pragma unroll
    for (int jj = 0; jj < 5; ++jj) {
        const uint4 ku = kus[jj];
        float d = q[0] * blo(ku.x) + q[1] * bhi(ku.x)
                + q[2] * blo(ku.y) + q[3] * bhi(ku.y)
                + q[4] * blo(ku.z) + q[5] * bhi(ku.z)
                + q[6] * blo(ku.w) + q[7] * bhi(ku.w);
        d += __shfl_xor(d, 1);
        d += __shfl_xor(d, 2);
        sc[jj] = d * scale;
    }

    float m = sc[0];
    #pragma unroll
    for (int jj = 1; jj < 5; ++jj) m = fmaxf(m, sc[jj]);
    m = fmaxf(m, __shfl_xor(m, 16));
    m = fmaxf(m, __shfl_xor(m, 32));

    float l = 0.f;
    float o[8] = {};
    #pragma unroll
    for (int jj = 0; jj < 5; ++jj) {
        const float e = __expf(sc[jj] - m);
        l += e;
        const uint4 vu = vus[jj];
        o[0] += e * blo(vu.x); o[1] += e * bhi(vu.x);
        o[2] += e * blo(vu.y); o[3] += e * bhi(vu.y);
        o[4] += e * blo(vu.z); o[5] += e * bhi(vu.z);
        o[6] += e * blo(vu.w); o[7] += e * bhi(vu.w);
    }

    l += __shfl_xor(l, 16); l += __shfl_xor(l, 32);
    #pragma unroll
    for (int i = 0; i < 8; ++i) {
        o[i] += __shfl_xor(o[i], 16);
        o[i] += __shfl_xor(o[i], 32);
    }
    if (s4 == 0) {
        const float inv = 1.f / l;
        uint4 ow;
        ow.x = pk(o[0] * inv, o[1] * inv);
        ow.y = pk(o[2] * inv, o[3] * inv);
        ow.z = pk(o[4] * inv, o[5] * inv);
        ow.w = pk(o[6] * inv, o[7] * inv);
        *(uint4*)(ctx + (size_t)node * 128 + p * 8) = ow;
    }
}

// ---------------------------------------------------------------------------
// Bucketed CSR build. (verified R4)
// ---------------------------------------------------------------------------
__global__ __launch_bounds__(256) void bcount_kernel(
    const int* __restrict__ esrc, int* __restrict__ bcnt, int E)
{
    __shared__ int hist[MAXB];
    for (int i = threadIdx.x; i < MAXB; i += 256) hist[i] = 0;
    __syncthreads();
    const int stride = gridDim.x * 256;
    for (int e = blockIdx.x * 256 + threadIdx.x; e < E; e += stride)
        atomicAdd(&hist[esrc[e] >> BSH], 1);
    __syncthreads();
    for (int i = threadIdx.x; i < MAXB; i += 256)
        if (hist[i]) atomicAdd(&bcnt[i], hist[i]);
}

__global__ void bscan_kernel(const int* __restrict__ bcnt, int* __restrict__ boffs,
                             int* __restrict__ bcur, int NB)
{
    if (threadIdx.x == 0 && blockIdx.x == 0) {
        int run = 0;
        for (int i = 0; i < NB; ++i) { boffs[i] = run; bcur[i] = run; run += bcnt[i]; }
        boffs[NB] = run;
    }
}

__global__ __launch_bounds__(256) void bscatter_kernel(
    const int* __restrict__ esrc, const int* __restrict__ edst,
    int* __restrict__ bcur, uint2* __restrict__ ebuck, int E)
{
    __shared__ int hist[MAXB], scanb[MAXB], lstart[MAXB], gbase[MAXB], cnt2[MAXB];
    __shared__ uint2 stage[2048];
    __shared__ int gaddr[2048];
    const int t = threadIdx.x;
    const int base = blockIdx.x * 2048;
    const int nchunk = min(2048, E - base);
    for (int i = t; i < MAXB; i += 256) { hist[i] = 0; cnt2[i] = 0; }
    __syncthreads();

    int es[8], ed[8], eb[8];
    #pragma unroll
    for (int i = 0; i < 8; ++i) {
        const int idx = base + i * 256 + t;
        if (idx < E) {
            es[i] = esrc[idx]; ed[i] = edst[idx];
            eb[i] = es[i] >> BSH;
            atomicAdd(&hist[eb[i]], 1);
        } else eb[i] = -1;
    }
    __syncthreads();

    if (t < MAXB) scanb[t] = hist[t];
    __syncthreads();
    for (int off = 1; off < MAXB; off <<= 1) {
        int v = 0;
        if (t < MAXB && t >= off) v = scanb[t - off];
        __syncthreads();
        if (t < MAXB) scanb[t] += v;
        __syncthreads();
    }
    if (t < MAXB) {
        lstart[t] = scanb[t] - hist[t];
        if (hist[t] > 0) gbase[t] = atomicAdd(&bcur[t], hist[t]);
    }
    __syncthreads();

    #pragma unroll
    for (int i = 0; i < 8; ++i) {
        if (eb[i] >= 0) {
            const int li = atomicAdd(&cnt2[eb[i]], 1);
            const int pos = lstart[eb[i]] + li;
            stage[pos] = make_uint2((unsigned)es[i], (unsigned)ed[i]);
            gaddr[pos] = gbase[eb[i]] + li;
        }
    }
    __syncthreads();
    for (int i = t; i < nchunk; i += 256)
        ebuck[gaddr[i]] = stage[i];
}

__global__ __launch_bounds__(256) void bbuild_kernel(
    const uint2* __restrict__ ebuck, const int* __restrict__ bcnt,
    const int* __restrict__ boffs, int* __restrict__ offs, int* __restrict__ csr, int N)
{
    __shared__ int degl[BW], sbuf[BW], curl[BW];
    const int b = blockIdx.x;
    const int t = threadIdx.x;
    const int nbase = b * BW;
    const int nn = min(BW, N - nbase);
    const int estart = boffs[b];
    const int ecnt = bcnt[b];

    for (int i = t; i < BW; i += 256) { degl[i] = 0; curl[i] = 0; }
    __syncthreads();
    for (int i = t; i < ecnt; i += 256)
        atomicAdd(&degl[(int)ebuck[estart + i].x - nbase], 1);
    __syncthreads();

    sbuf[t] = degl[t]; sbuf[t + 256] = degl[t + 256];
    __syncthreads();
    for (int off = 1; off < BW; off <<= 1) {
        const int i1 = t + 256;
        int v0 = (t  >= off) ? sbuf[t  - off] : 0;
        int v1 = (i1 >= off) ? sbuf[i1 - off] : 0;
        __syncthreads();
        sbuf[t] += v0; sbuf[i1] += v1;
        __syncthreads();
    }
    {
        const int e0 = sbuf[t] - degl[t];
        const int e1 = sbuf[t + 256] - degl[t + 256];
        sbuf[t] = e0; sbuf[t + 256] = e1;
        if (t < nn)       offs[nbase + t]       = estart + e0;
        if (t + 256 < nn) offs[nbase + t + 256] = estart + e1;
    }
    __syncthreads();
    for (int i = t; i < ecnt; i += 256) {
        const uint2 pr = ebuck[estart + i];
        const int s = (int)pr.x - nbase;
        const int pos = estart + sbuf[s] + atomicAdd(&curl[s], 1);
        csr[pos] = (int)pr.y;
    }
}

// ---------------------------------------------------------------------------
// Aggregation: wave/node, 4 edge slots x 4-deep unroll (16 loads in flight)
// ---------------------------------------------------------------------------
__global__ __launch_bounds__(256) void aggregate_kernel(
    const unsigned short* __restrict__ hb, const int* __restrict__ offs,
    const int* __restrict__ csr, unsigned short* __restrict__ outp, int n, int E)
{
    const int node = blockIdx.x * 4 + (threadIdx.x >> 6);
    const int lane = threadIdx.x & 63;
    if (node >= n) return;
    const int e4 = lane >> 4;
    const int p  = lane & 15;
    const int s = offs[node];
    const int e = (node == n - 1) ? E : offs[node + 1];
    float a[8] = {};
    int i = s + e4;
    for (; i + 12 < e; i += 16) {
        const int d0 = csr[i], d1 = csr[i + 4], d2 = csr[i + 8], d3 = csr[i + 12];
        const uint4 u0 = *(const uint4*)(hb + (size_t)d0 * 128 + p * 8);
        const uint4 u1 = *(const uint4*)(hb + (size_t)d1 * 128 + p * 8);
        const uint4 u2 = *(const uint4*)(hb + (size_t)d2 * 128 + p * 8);
        const uint4 u3 = *(const uint4*)(hb + (size_t)d3 * 128 + p * 8);
        a[0] += blo(u0.x) + blo(u1.x) + blo(u2.x) + blo(u3.x);
        a[1] += bhi(u0.x) + bhi(u1.x) + bhi(u2.x) + bhi(u3.x);
        a[2] += blo(u0.y) + blo(u1.y) + blo(u2.y) + blo(u3.y);
        a[3] += bhi(u0.y) + bhi(u1.y) + bhi(u2.y) + bhi(u3.y);
        a[4] += blo(u0.z) + blo(u1.z) + blo(u2.z) + blo(u3.z);
        a[5] += bhi(u0.z) + bhi(u1.z) + bhi(u2.z) + bhi(u3.z);
        a[6] += blo(u0.w) + blo(u1.w) + blo(u2.w) + blo(u3.w);
        a[7] += bhi(u0.w) + bhi(u1.w) + bhi(u2.w) + bhi(u3.w);
    }
    for (; i < e; i += 4) {
        const uint4 u = *(const uint4*)(hb + (size_t)csr[i] * 128 + p * 8);
        a[0] += blo(u.x); a[1] += bhi(u.x);
        a[2] += blo(u.y); a[3] += bhi(u.y);
        a[4] += blo(u.z); a[5] += bhi(u.z);
        a[6] += blo(u.w); a[7] += bhi(u.w);
    }
    #pragma unroll
    for (int k = 0; k < 8; ++k) {
        a[k] += __shfl_xor(a[k], 16);
        a[k] += __shfl_xor(a[k], 32);
    }
    if (e4 == 0) {
        uint4 ow;
        ow.x = pk(a[0], a[1]); ow.y = pk(a[2], a[3]);
        ow.z = pk(a[4], a[5]); ow.w = pk(a[6], a[7]);
        *(uint4*)(outp + (size_t)node * 128 + p * 8) = ow;
    }
}

// ---------------------------------------------------------------------------
extern "C" void kernel_launch(void* const* d_in, const int* in_sizes, int n_in,
                              void* d_out, int out_size, void* d_ws, size_t ws_size,
                              hipStream_t stream)
{
    const float* x        = (const float*)d_in[0];
    const int*   samples  = (const int*)d_in[1];
    const int*   esrc     = (const int*)d_in[2];
    const int*   edst     = (const int*)d_in[3];
    const float* t_in_w   = (const float*)d_in[4];   // [3][384][128]
    const float* t_in_b   = (const float*)d_in[5];
    const float* t_out_w  = (const float*)d_in[6];   // [3][128][128]
    const float* t_out_b  = (const float*)d_in[7];
    const float* t_ffn_w1 = (const float*)d_in[8];   // [3][512][128]
    const float* t_ffn_b1 = (const float*)d_in[9];
    const float* t_ffn_w2 = (const float*)d_in[10];  // [3][128][512]
    const float* t_ffn_b2 = (const float*)d_in[11];
    const float* t_ln1_g  = (const float*)d_in[12];
    const float* t_ln1_b  = (const float*)d_in[13];
    const float* t_ln2_g  = (const float*)d_in[14];
    const float* t_ln2_b  = (const float*)d_in[15];
    const float* g_w      = (const float*)d_in[16];  // [2][128][256]
    const float* g_b      = (const float*)d_in[17];
    const float* g_ln_g   = (const float*)d_in[18];
    const float* g_ln_b   = (const float*)d_in[19];

    const int N = in_sizes[0] / DM;
    const int E = in_sizes[2];
    const int NB = (N + BW - 1) >> BSH;

    float* h = (float*)d_out;                        // [N][128] fp32 hidden

    // ---- workspace layout ----
    unsigned short* wbuf = (unsigned short*)d_ws;    // bf16 weights (wcvt layout)
    unsigned short* w_in  = wbuf;                    // 3*384*128 = 147456
    unsigned short* w_out = w_in  + 147456;          // 3*128*128 = 49152
    unsigned short* w_f1  = w_out + 49152;           // 3*512*128 = 196608
    unsigned short* w_f2  = w_f1  + 196608;          // 3*128*512 = 196608
    unsigned short* w_g   = w_f2  + 196608;          // 2*128*256 = 65536
    unsigned short* hb    = w_g   + 65536;           // [N][128] bf16 hidden
    unsigned short* Abf   = hb  + (size_t)N * 128;   // [N][384] QKV
    unsigned short* Bbf   = Abf + (size_t)N * 384;   // [N][128] ctx / neigh
    uint2* ebuck = (uint2*)(Bbf + (size_t)N * 128);  // [E]
    int* offs = (int*)(ebuck + E);                   // [N]
    int* csr  = offs + N;                            // [E]
    int* bcnt  = csr + E;                            // [MAXB]
    int* boffs = bcnt + MAXB;                        // [MAXB+1]
    int* bcur  = boffs + MAXB + 1;                   // [MAXB]

    const int mt = (N + 63) / 64;
    const int mt2 = (N + 127) / 128;
    const dim3 blk(256);

    xcvt_kernel<<<((N * DM) / 4 + 255) / 256, blk, 0, stream>>>(x, h, hb, N * DM);
    wcvt_kernel<<<(655360 / 4 + 255) / 256, blk, 0, stream>>>(
        t_in_w, t_out_w, t_ffn_w1, t_ffn_w2, g_w, wbuf);

    // ---- bucketed CSR build ----
    hipMemsetAsync(bcnt, 0, MAXB * sizeof(int), stream);
    bcount_kernel<<<(E + 2047) / 2048, blk, 0, stream>>>(esrc, bcnt, E);
    bscan_kernel<<<1, 64, 0, stream>>>(bcnt, boffs, bcur, NB);
    bscatter_kernel<<<(E + 2047) / 2048, blk, 0, stream>>>(esrc, edst, bcur, ebuck, E);
    bbuild_kernel<<<NB, blk, 0, stream>>>(ebuck, bcnt, boffs, offs, csr, N);

    const int pn_grid = (N + 3) / 4;

    for (int layer = 0; layer < 5; ++layer) {
        if (layer == 1 || layer == 3) {
            // ---------------- GNN block ----------------
            const int i = (layer == 1) ? 0 : 1;
            aggregate_kernel<<<pn_grid, blk, 0, stream>>>(hb, offs, csr, Bbf, N, E);
            gemm_ln<256, true, 128><<<mt, blk, 0, stream>>>(
                hb, Bbf, w_g + (size_t)i * 32768, g_b + i * 128, h,
                g_ln_g + i * 128, g_ln_b + i * 128, h, hb, N);
        } else {
            // ---------------- Transformer block ----------------
            const int i = (layer == 0) ? 0 : (layer == 2 ? 1 : 2);
            gemm_mfma<128, 384, false><<<dim3(mt2, 6), blk, 0, stream>>>(
                hb, w_in + (size_t)i * 49152, t_in_b + i * 384, Abf, N);
            attn_kernel<<<pn_grid, blk, 0, stream>>>(Abf, samples, Bbf, N);
            gemm_ln<128, false, 0><<<mt, blk, 0, stream>>>(
                Bbf, nullptr, w_out + (size_t)i * 16384, t_out_b + i * 128, h,
                t_ln1_g + i * 128, t_ln1_b + i * 128, h, hb, N);
            ffn_fused<<<mt, blk, 0, stream>>>(
                hb, w_f1 + (size_t)i * 65536, t_ffn_b1 + i * 512,
                w_f2 + (size_t)i * 65536, t_ffn_b2 + i * 128, h,
                t_ln2_g + i * 128, t_ln2_b + i * 128, h, hb, N);
        }
    }
}